// Round 1
// baseline (1042.612 us; speedup 1.0000x reference)
//
#include <hip/hip_runtime.h>
#include <math.h>

// Model dims
#define TDIM 1024   // context len
#define FDIM 1024
#define DDIM 512
#define NB   32

__device__ __forceinline__ float posenc_val(int t, int c) {
    int j = c >> 1;
    float dv = expf(-9.210340371976184f * (float)(2 * j) * (1.0f / 512.0f));
    float arg = (float)t * dv;
    return (c & 1) ? cosf(arg) : sinf(arg);
}

// ---------------- Tiled fp32 GEMM: C = act(A @ B + bias) [+posenc] ----------------
// A: MxK (lda), B: KxN (ldb), C: MxN (ldc). M%64==0, N%64==0, K%16==0.
#define TM 64
#define TN 64
#define TK 16

__global__ __launch_bounds__(256)
void gemm_f32(const float* __restrict__ A, int lda,
              const float* __restrict__ B, int ldb,
              const float* __restrict__ bias,
              float* __restrict__ C, int ldc,
              int M, int N, int K, int do_relu, int addpe)
{
    __shared__ float As[TK][TM + 4];
    __shared__ float Bs[TK][TN + 4];
    const int tid = threadIdx.x;
    const int bm = blockIdx.y * TM;
    const int bn = blockIdx.x * TN;
    const int tx = tid & 15, ty = tid >> 4;

    float acc[4][4] = {};

    for (int k0 = 0; k0 < K; k0 += TK) {
        // load A tile (64 x 16)
        #pragma unroll
        for (int p = 0; p < 4; ++p) {
            int r  = (tid >> 4) + p * 16;
            int kk = tid & 15;
            As[kk][r] = A[(size_t)(bm + r) * lda + k0 + kk];
        }
        // load B tile (16 x 64)
        #pragma unroll
        for (int p = 0; p < 4; ++p) {
            int kk = (tid >> 6) + p * 4;
            int c  = tid & 63;
            Bs[kk][c] = B[(size_t)(k0 + kk) * ldb + bn + c];
        }
        __syncthreads();
        #pragma unroll
        for (int kk = 0; kk < TK; ++kk) {
            float a[4], b[4];
            #pragma unroll
            for (int i = 0; i < 4; ++i) a[i] = As[kk][ty * 4 + i];
            #pragma unroll
            for (int j = 0; j < 4; ++j) b[j] = Bs[kk][tx * 4 + j];
            #pragma unroll
            for (int i = 0; i < 4; ++i)
                #pragma unroll
                for (int j = 0; j < 4; ++j)
                    acc[i][j] = fmaf(a[i], b[j], acc[i][j]);
        }
        __syncthreads();
    }

    #pragma unroll
    for (int i = 0; i < 4; ++i) {
        int m = bm + ty * 4 + i;
        #pragma unroll
        for (int j = 0; j < 4; ++j) {
            int n = bn + tx * 4 + j;
            float v = acc[i][j] + bias[n];
            if (do_relu) v = fmaxf(v, 0.f);
            if (addpe)   v += posenc_val(m, n);
            C[(size_t)m * ldc + n] = v;
        }
    }
}

// ---------------- encoder MLP for the 32 last-timestep rows ----------------
__global__ __launch_bounds__(256)
void enc_last_rows(const float* __restrict__ features,
                   const float* __restrict__ w1, const float* __restrict__ b1,
                   const float* __restrict__ w2, const float* __restrict__ b2,
                   float* __restrict__ ylast)
{
    __shared__ float x[FDIM];
    __shared__ float h[DDIM];
    const int b = blockIdx.x;
    const int tid = threadIdx.x;
    const float* row = features + ((size_t)b * TDIM + (TDIM - 1)) * FDIM;
    for (int i = tid; i < FDIM; i += 256) x[i] = row[i];
    __syncthreads();
    for (int c = tid; c < DDIM; c += 256) {
        float s = b1[c];
        for (int k = 0; k < FDIM; ++k) s = fmaf(x[k], w1[(size_t)k * DDIM + c], s);
        h[c] = fmaxf(s, 0.f);
    }
    __syncthreads();
    for (int c = tid; c < DDIM; c += 256) {
        float s = b2[c];
        for (int k = 0; k < DDIM; ++k) s = fmaf(h[k], w2[(size_t)k * DDIM + c], s);
        s = fmaxf(s, 0.f) + posenc_val(TDIM - 1, c);
        ylast[b * DDIM + c] = s;
    }
}

// ---------------- Q rows: Q32[i] = Y31[32*i+31] @ qkv_w[:, :512] + qkv_b[:512] ----------------
__global__ __launch_bounds__(256)
void q_rows(const float* __restrict__ Y31, const float* __restrict__ qkv_w,
            const float* __restrict__ qkv_b, float* __restrict__ Q32)
{
    __shared__ float y[DDIM];
    const int i = blockIdx.x;
    const int t = 32 * i + 31;
    const int tid = threadIdx.x;
    for (int k = tid; k < DDIM; k += 256) y[k] = Y31[(size_t)t * DDIM + k];
    __syncthreads();
    for (int c = tid; c < DDIM; c += 256) {
        float s = qkv_b[c];
        for (int k = 0; k < DDIM; ++k) s = fmaf(y[k], qkv_w[(size_t)k * 1536 + c], s);
        Q32[i * DDIM + c] = s;
    }
}

// ---------------- differential dual-softmax attention for 32 query rows ----------------
// KV layout: row t = [K(512) | V(512)], ld = 1024
__global__ __launch_bounds__(256)
void attn_kernel(const float* __restrict__ Q32, const float* __restrict__ KV,
                 const float* __restrict__ lam_p, float* __restrict__ attn32)
{
    __shared__ float q[DDIM];
    __shared__ float sc1[TDIM];
    __shared__ float sc2[TDIM];
    __shared__ float red[256];
    const int i = blockIdx.x;
    const int tid = threadIdx.x;
    for (int k = tid; k < DDIM; k += 256) q[k] = Q32[i * DDIM + k];
    __syncthreads();
    const float scale = 0.08838834764831845f; // 1/sqrt(128)
    for (int s = tid; s < TDIM; s += 256) {
        const float4* kr = (const float4*)(KV + (size_t)s * 1024);
        float d1 = 0.f, d2 = 0.f;
        #pragma unroll 4
        for (int k4 = 0; k4 < 64; ++k4) {
            float4 ka = kr[k4];
            d1 = fmaf(q[4 * k4 + 0], ka.x, d1);
            d1 = fmaf(q[4 * k4 + 1], ka.y, d1);
            d1 = fmaf(q[4 * k4 + 2], ka.z, d1);
            d1 = fmaf(q[4 * k4 + 3], ka.w, d1);
            float4 kb = kr[64 + k4];
            d2 = fmaf(q[256 + 4 * k4 + 0], kb.x, d2);
            d2 = fmaf(q[256 + 4 * k4 + 1], kb.y, d2);
            d2 = fmaf(q[256 + 4 * k4 + 2], kb.z, d2);
            d2 = fmaf(q[256 + 4 * k4 + 3], kb.w, d2);
        }
        sc1[s] = d1 * scale;
        sc2[s] = d2 * scale;
    }
    __syncthreads();
    // max of sc1
    float m1 = -INFINITY, m2 = -INFINITY;
    for (int s = tid; s < TDIM; s += 256) { m1 = fmaxf(m1, sc1[s]); m2 = fmaxf(m2, sc2[s]); }
    red[tid] = m1; __syncthreads();
    for (int o = 128; o > 0; o >>= 1) { if (tid < o) red[tid] = fmaxf(red[tid], red[tid + o]); __syncthreads(); }
    m1 = red[0]; __syncthreads();
    red[tid] = m2; __syncthreads();
    for (int o = 128; o > 0; o >>= 1) { if (tid < o) red[tid] = fmaxf(red[tid], red[tid + o]); __syncthreads(); }
    m2 = red[0]; __syncthreads();
    // sums
    float t1 = 0.f, t2 = 0.f;
    for (int s = tid; s < TDIM; s += 256) { t1 += expf(sc1[s] - m1); t2 += expf(sc2[s] - m2); }
    red[tid] = t1; __syncthreads();
    for (int o = 128; o > 0; o >>= 1) { if (tid < o) red[tid] += red[tid + o]; __syncthreads(); }
    t1 = red[0]; __syncthreads();
    red[tid] = t2; __syncthreads();
    for (int o = 128; o > 0; o >>= 1) { if (tid < o) red[tid] += red[tid + o]; __syncthreads(); }
    t2 = red[0]; __syncthreads();
    const float inv1 = 1.f / t1, inv2 = 1.f / t2;
    const float lam = *lam_p;
    for (int s = tid; s < TDIM; s += 256)
        sc1[s] = expf(sc1[s] - m1) * inv1 - lam * expf(sc2[s] - m2) * inv2;
    __syncthreads();
    // PV
    for (int d = tid; d < DDIM; d += 256) {
        float acc = 0.f;
        for (int s = 0; s < TDIM; ++s) acc = fmaf(sc1[s], KV[(size_t)s * 1024 + 512 + d], acc);
        attn32[i * DDIM + d] = acc;
    }
}

// ---------------- 32-row dense layer: Y[m,n] = act(X[m,:] @ W + bias) ----------------
// grid: (N/256, 32); dynamic LDS = K*4 bytes
__global__ __launch_bounds__(256)
void rowmlp(const float* __restrict__ X, int ldx,
            const float* __restrict__ W, const float* __restrict__ bias,
            float* __restrict__ Y, int ldy,
            int K, int N, int do_relu)
{
    extern __shared__ float xrow[];
    const int m = blockIdx.y;
    const int n = blockIdx.x * 256 + threadIdx.x;
    for (int k = threadIdx.x; k < K; k += 256) xrow[k] = X[(size_t)m * ldx + k];
    __syncthreads();
    float s = bias[n];
    for (int k = 0; k < K; ++k) s = fmaf(xrow[k], W[(size_t)k * N + n], s);
    if (do_relu) s = fmaxf(s, 0.f);
    Y[(size_t)m * ldy + n] = s;
}

// ---------------- LayerNorm over 512: Y = LN(X + R) * g + b ----------------
__global__ __launch_bounds__(256)
void ln_kernel(const float* __restrict__ X, const float* __restrict__ R,
               const float* __restrict__ g, const float* __restrict__ b,
               float* __restrict__ Y)
{
    __shared__ float red[256];
    const int m = blockIdx.x;
    const int tid = threadIdx.x;
    float v0 = X[m * DDIM + tid]       + R[m * DDIM + tid];
    float v1 = X[m * DDIM + 256 + tid] + R[m * DDIM + 256 + tid];
    red[tid] = v0 + v1; __syncthreads();
    for (int o = 128; o > 0; o >>= 1) { if (tid < o) red[tid] += red[tid + o]; __syncthreads(); }
    const float mu = red[0] * (1.0f / 512.0f);
    __syncthreads();
    float d0 = v0 - mu, d1 = v1 - mu;
    red[tid] = d0 * d0 + d1 * d1; __syncthreads();
    for (int o = 128; o > 0; o >>= 1) { if (tid < o) red[tid] += red[tid + o]; __syncthreads(); }
    const float var = red[0] * (1.0f / 512.0f);
    const float inv = 1.0f / sqrtf(var + 1e-5f);
    Y[m * DDIM + tid]       = d0 * inv * g[tid]       + b[tid];
    Y[m * DDIM + 256 + tid] = d1 * inv * g[256 + tid] + b[256 + tid];
}

extern "C" void kernel_launch(void* const* d_in, const int* in_sizes, int n_in,
                              void* d_out, int out_size, void* d_ws, size_t ws_size,
                              hipStream_t stream)
{
    const float* features = (const float*)d_in[0];
    const float* enc_w1 = (const float*)d_in[1];
    const float* enc_b1 = (const float*)d_in[2];
    const float* enc_w2 = (const float*)d_in[3];
    const float* enc_b2 = (const float*)d_in[4];
    const float* qkv_w  = (const float*)d_in[5];
    const float* qkv_b  = (const float*)d_in[6];
    const float* lam    = (const float*)d_in[7];
    const float* out_w  = (const float*)d_in[8];
    const float* out_b  = (const float*)d_in[9];
    const float* ln1_g  = (const float*)d_in[10];
    const float* ln1_b  = (const float*)d_in[11];
    const float* ffn_w1 = (const float*)d_in[12];
    const float* ffn_b1 = (const float*)d_in[13];
    const float* ffn_w2 = (const float*)d_in[14];
    const float* ffn_b2 = (const float*)d_in[15];
    const float* ln2_g  = (const float*)d_in[16];
    const float* ln2_b  = (const float*)d_in[17];
    const float* act_w1 = (const float*)d_in[18];
    const float* act_b1 = (const float*)d_in[19];
    const float* act_w2 = (const float*)d_in[20];
    const float* act_b2 = (const float*)d_in[21];
    const float* act_w3 = (const float*)d_in[22];
    const float* act_b3 = (const float*)d_in[23];
    const float* cr_w1  = (const float*)d_in[24];
    const float* cr_b1  = (const float*)d_in[25];
    const float* cr_w2  = (const float*)d_in[26];
    const float* cr_b2  = (const float*)d_in[27];
    const float* cr_w3  = (const float*)d_in[28];
    const float* cr_b3  = (const float*)d_in[29];
    float* out = (float*)d_out;

    // workspace layout (floats): ~9.3 MB total
    float* ws = (float*)d_ws;
    float* H1      = ws;                   // 1024*512
    float* Y31     = H1 + 1024 * 512;      // 1024*512
    float* KV      = Y31 + 1024 * 512;     // 1024*1024
    float* Q32     = KV + 1024 * 1024;     // 32*512
    float* ylast   = Q32 + 32 * 512;       // 32*512
    float* attn32  = ylast + 32 * 512;     // 32*512
    float* attnprj = attn32 + 32 * 512;    // 32*512
    float* y1      = attnprj + 32 * 512;   // 32*512
    float* y2      = y1 + 32 * 512;        // 32*512
    float* zbuf    = y2 + 32 * 512;        // 32*512
    float* hbuf    = zbuf + 32 * 512;      // 32*1024
    float* hbuf2   = hbuf + 32 * 1024;     // 32*2048

    dim3 blk(256);

    // encoder for batch 31 (full sequence)
    gemm_f32<<<dim3(DDIM / TN, TDIM / TM), blk, 0, stream>>>(
        features + (size_t)31 * TDIM * FDIM, FDIM, enc_w1, DDIM, enc_b1,
        H1, DDIM, TDIM, DDIM, FDIM, 1, 0);
    gemm_f32<<<dim3(DDIM / TN, TDIM / TM), blk, 0, stream>>>(
        H1, DDIM, enc_w2, DDIM, enc_b2,
        Y31, DDIM, TDIM, DDIM, DDIM, 1, 1);
    // K,V for batch 31 (qkv_w columns 512:1536)
    gemm_f32<<<dim3(1024 / TN, TDIM / TM), blk, 0, stream>>>(
        Y31, DDIM, qkv_w + 512, 1536, qkv_b + 512,
        KV, 1024, TDIM, 1024, DDIM, 0, 0);
    // last-timestep encoder rows for all 32 batches
    enc_last_rows<<<32, blk, 0, stream>>>(features, enc_w1, enc_b1, enc_w2, enc_b2, ylast);
    // 32 Q rows of batch 31 (t = 32*i + 31)
    q_rows<<<32, blk, 0, stream>>>(Y31, qkv_w, qkv_b, Q32);
    // attention (dual softmax, diff, PV)
    attn_kernel<<<32, blk, 0, stream>>>(Q32, KV, lam, attn32);
    // out projection
    rowmlp<<<dim3(2, 32), blk, 512 * 4, stream>>>(attn32, 512, out_w, out_b, attnprj, 512, 512, 512, 0);
    // LN1
    ln_kernel<<<32, blk, 0, stream>>>(ylast, attnprj, ln1_g, ln1_b, y1);
    // FFN
    rowmlp<<<dim3(4, 32), blk, 512 * 4, stream>>>(y1, 512, ffn_w1, ffn_b1, hbuf, 1024, 512, 1024, 1);
    rowmlp<<<dim3(2, 32), blk, 1024 * 4, stream>>>(hbuf, 1024, ffn_w2, ffn_b2, zbuf, 512, 1024, 512, 0);
    // LN2
    ln_kernel<<<32, blk, 0, stream>>>(y1, zbuf, ln2_g, ln2_b, y2);
    // actor head -> out[0:8192]
    rowmlp<<<dim3(4, 32), blk, 512 * 4, stream>>>(y2, 512, act_w1, act_b1, hbuf, 1024, 512, 1024, 1);
    rowmlp<<<dim3(8, 32), blk, 1024 * 4, stream>>>(hbuf, 1024, act_w2, act_b2, hbuf2, 2048, 1024, 2048, 1);
    rowmlp<<<dim3(1, 32), blk, 2048 * 4, stream>>>(hbuf2, 2048, act_w3, act_b3, out, 256, 2048, 256, 0);
    // critic head -> out[8192:16384]
    rowmlp<<<dim3(4, 32), blk, 512 * 4, stream>>>(y2, 512, cr_w1, cr_b1, hbuf, 1024, 512, 1024, 1);
    rowmlp<<<dim3(8, 32), blk, 1024 * 4, stream>>>(hbuf, 1024, cr_w2, cr_b2, hbuf2, 2048, 1024, 2048, 1);
    rowmlp<<<dim3(1, 32), blk, 2048 * 4, stream>>>(hbuf2, 2048, cr_w3, cr_b3, out + 8192, 256, 2048, 256, 0);
}

// Round 2
// 385.172 us; speedup vs baseline: 2.7069x; 2.7069x over previous
//
#include <hip/hip_runtime.h>
#include <math.h>

// Model dims
#define TDIM 1024   // context len
#define FDIM 1024
#define DDIM 512

__device__ __forceinline__ float posenc_val(int t, int c) {
    int j = c >> 1;
    float dv = expf(-9.210340371976184f * (float)(2 * j) * (1.0f / 512.0f));
    float arg = (float)t * dv;
    return (c & 1) ? cosf(arg) : sinf(arg);
}

// ---------------- Tiled fp32 GEMM: C = act(A @ B + bias) [+posenc] ----------------
#define TM 64
#define TN 64
#define TK 16

__global__ __launch_bounds__(256)
void gemm_f32(const float* __restrict__ A, int lda,
              const float* __restrict__ B, int ldb,
              const float* __restrict__ bias,
              float* __restrict__ C, int ldc,
              int M, int N, int K, int do_relu, int addpe)
{
    __shared__ float As[TK][TM + 4];
    __shared__ float Bs[TK][TN + 4];
    const int tid = threadIdx.x;
    const int bm = blockIdx.y * TM;
    const int bn = blockIdx.x * TN;
    const int tx = tid & 15, ty = tid >> 4;

    float acc[4][4] = {};

    for (int k0 = 0; k0 < K; k0 += TK) {
        #pragma unroll
        for (int p = 0; p < 4; ++p) {
            int r  = (tid >> 4) + p * 16;
            int kk = tid & 15;
            As[kk][r] = A[(size_t)(bm + r) * lda + k0 + kk];
        }
        #pragma unroll
        for (int p = 0; p < 4; ++p) {
            int kk = (tid >> 6) + p * 4;
            int c  = tid & 63;
            Bs[kk][c] = B[(size_t)(k0 + kk) * ldb + bn + c];
        }
        __syncthreads();
        #pragma unroll
        for (int kk = 0; kk < TK; ++kk) {
            float a[4], b[4];
            #pragma unroll
            for (int i = 0; i < 4; ++i) a[i] = As[kk][ty * 4 + i];
            #pragma unroll
            for (int j = 0; j < 4; ++j) b[j] = Bs[kk][tx * 4 + j];
            #pragma unroll
            for (int i = 0; i < 4; ++i)
                #pragma unroll
                for (int j = 0; j < 4; ++j)
                    acc[i][j] = fmaf(a[i], b[j], acc[i][j]);
        }
        __syncthreads();
    }

    #pragma unroll
    for (int i = 0; i < 4; ++i) {
        int m = bm + ty * 4 + i;
        #pragma unroll
        for (int j = 0; j < 4; ++j) {
            int n = bn + tx * 4 + j;
            float v = acc[i][j] + bias[n];
            if (do_relu) v = fmaxf(v, 0.f);
            if (addpe)   v += posenc_val(m, n);
            C[(size_t)m * ldc + n] = v;
        }
    }
}

// ---------------- split-K small-M GEMM: P[kc] = A(32xBK slice) @ B(BKx64 tile) ----------------
// grid: (N/64, K/BK). Partials P[kc][32][N].
template<int BK>
__global__ __launch_bounds__(256)
void gemm32(const float* __restrict__ A, long lda,
            const float* __restrict__ B, long ldb,
            float* __restrict__ P, int N)
{
    __shared__ float Xs[32][BK + 4];
    __shared__ float Ws[BK][64];
    const int tid = threadIdx.x;
    const int n0 = blockIdx.x * 64;
    const int k0 = blockIdx.y * BK;

    // X tile: 32 x BK, coalesced along k
    {
        const int m  = tid >> 3;
        const int ks = (tid & 7) * (BK / 8);
        const float* src = A + (size_t)m * lda + k0 + ks;
        #pragma unroll
        for (int j = 0; j < BK / 32; ++j) {
            float4 v = *(const float4*)(src + j * 4);
            *(float4*)&Xs[m][ks + j * 4] = v;
        }
    }
    // W tile: BK x 64, coalesced along n
    #pragma unroll
    for (int it = 0; it < BK / 16; ++it) {
        int e4  = it * 256 + tid;   // float4 index, 16 per row
        int row = e4 >> 4;
        int c4  = e4 & 15;
        float4 v = *(const float4*)(B + (size_t)(k0 + row) * ldb + n0 + c4 * 4);
        *(float4*)&Ws[row][c4 * 4] = v;
    }
    __syncthreads();

    const int tx = tid & 31;   // n-pair
    const int ty = tid >> 5;   // m-quad
    float acc[4][2] = {};
    #pragma unroll 8
    for (int k = 0; k < BK; k += 4) {
        float4 xv[4];
        #pragma unroll
        for (int i = 0; i < 4; ++i) xv[i] = *(const float4*)&Xs[ty * 4 + i][k];
        #pragma unroll
        for (int j = 0; j < 4; ++j) {
            float2 w = *(const float2*)&Ws[k + j][tx * 2];
            #pragma unroll
            for (int i = 0; i < 4; ++i) {
                float x = ((const float*)&xv[i])[j];
                acc[i][0] = fmaf(x, w.x, acc[i][0]);
                acc[i][1] = fmaf(x, w.y, acc[i][1]);
            }
        }
    }

    float* dst = P + (size_t)blockIdx.y * 32 * N;
    #pragma unroll
    for (int i = 0; i < 4; ++i) {
        float2 v = make_float2(acc[i][0], acc[i][1]);
        *(float2*)(dst + (size_t)(ty * 4 + i) * N + n0 + tx * 2) = v;
    }
}

// ---------------- finalize: Y = act(sum_kc P + bias) [+posenc(perow)] ----------------
__global__ __launch_bounds__(256)
void finalize(const float* __restrict__ P, int KC, int N,
              const float* __restrict__ bias, float* __restrict__ Y, int ldy,
              int do_relu, int perow)
{
    const int n = blockIdx.x * 256 + threadIdx.x;
    const int m = blockIdx.y;
    float s = bias[n];
    for (int kc = 0; kc < KC; ++kc) s += P[(size_t)(kc * 32 + m) * N + n];
    if (do_relu) s = fmaxf(s, 0.f);
    if (perow >= 0) s += posenc_val(perow, n);
    Y[(size_t)m * ldy + n] = s;
}

// ---------------- differential dual-softmax attention for 32 query rows ----------------
__global__ __launch_bounds__(256)
void attn_kernel(const float* __restrict__ Q32, const float* __restrict__ KV,
                 const float* __restrict__ lam_p, float* __restrict__ attn32)
{
    __shared__ float q[DDIM];
    __shared__ float sc1[TDIM];
    __shared__ float sc2[TDIM];
    __shared__ float red[256];
    const int i = blockIdx.x;
    const int tid = threadIdx.x;
    for (int k = tid; k < DDIM; k += 256) q[k] = Q32[i * DDIM + k];
    __syncthreads();
    const float scale = 0.08838834764831845f; // 1/sqrt(128)
    for (int s = tid; s < TDIM; s += 256) {
        const float4* kr = (const float4*)(KV + (size_t)s * 1024);
        float d1 = 0.f, d2 = 0.f;
        #pragma unroll 4
        for (int k4 = 0; k4 < 64; ++k4) {
            float4 ka = kr[k4];
            d1 = fmaf(q[4 * k4 + 0], ka.x, d1);
            d1 = fmaf(q[4 * k4 + 1], ka.y, d1);
            d1 = fmaf(q[4 * k4 + 2], ka.z, d1);
            d1 = fmaf(q[4 * k4 + 3], ka.w, d1);
            float4 kb = kr[64 + k4];
            d2 = fmaf(q[256 + 4 * k4 + 0], kb.x, d2);
            d2 = fmaf(q[256 + 4 * k4 + 1], kb.y, d2);
            d2 = fmaf(q[256 + 4 * k4 + 2], kb.z, d2);
            d2 = fmaf(q[256 + 4 * k4 + 3], kb.w, d2);
        }
        sc1[s] = d1 * scale;
        sc2[s] = d2 * scale;
    }
    __syncthreads();
    float m1 = -INFINITY, m2 = -INFINITY;
    for (int s = tid; s < TDIM; s += 256) { m1 = fmaxf(m1, sc1[s]); m2 = fmaxf(m2, sc2[s]); }
    red[tid] = m1; __syncthreads();
    for (int o = 128; o > 0; o >>= 1) { if (tid < o) red[tid] = fmaxf(red[tid], red[tid + o]); __syncthreads(); }
    m1 = red[0]; __syncthreads();
    red[tid] = m2; __syncthreads();
    for (int o = 128; o > 0; o >>= 1) { if (tid < o) red[tid] = fmaxf(red[tid], red[tid + o]); __syncthreads(); }
    m2 = red[0]; __syncthreads();
    float t1 = 0.f, t2 = 0.f;
    for (int s = tid; s < TDIM; s += 256) { t1 += expf(sc1[s] - m1); t2 += expf(sc2[s] - m2); }
    red[tid] = t1; __syncthreads();
    for (int o = 128; o > 0; o >>= 1) { if (tid < o) red[tid] += red[tid + o]; __syncthreads(); }
    t1 = red[0]; __syncthreads();
    red[tid] = t2; __syncthreads();
    for (int o = 128; o > 0; o >>= 1) { if (tid < o) red[tid] += red[tid + o]; __syncthreads(); }
    t2 = red[0]; __syncthreads();
    const float inv1 = 1.f / t1, inv2 = 1.f / t2;
    const float lam = *lam_p;
    for (int s = tid; s < TDIM; s += 256)
        sc1[s] = expf(sc1[s] - m1) * inv1 - lam * expf(sc2[s] - m2) * inv2;
    __syncthreads();
    for (int d = tid; d < DDIM; d += 256) {
        float acc = 0.f;
        for (int s = 0; s < TDIM; ++s) acc = fmaf(sc1[s], KV[(size_t)s * 1024 + 512 + d], acc);
        attn32[i * DDIM + d] = acc;
    }
}

// ---------------- LayerNorm over 512: Y = LN(X + R) * g + b ----------------
__global__ __launch_bounds__(256)
void ln_kernel(const float* __restrict__ X, const float* __restrict__ R,
               const float* __restrict__ g, const float* __restrict__ b,
               float* __restrict__ Y)
{
    __shared__ float red[256];
    const int m = blockIdx.x;
    const int tid = threadIdx.x;
    float v0 = X[m * DDIM + tid]       + R[m * DDIM + tid];
    float v1 = X[m * DDIM + 256 + tid] + R[m * DDIM + 256 + tid];
    red[tid] = v0 + v1; __syncthreads();
    for (int o = 128; o > 0; o >>= 1) { if (tid < o) red[tid] += red[tid + o]; __syncthreads(); }
    const float mu = red[0] * (1.0f / 512.0f);
    __syncthreads();
    float d0 = v0 - mu, d1 = v1 - mu;
    red[tid] = d0 * d0 + d1 * d1; __syncthreads();
    for (int o = 128; o > 0; o >>= 1) { if (tid < o) red[tid] += red[tid + o]; __syncthreads(); }
    const float var = red[0] * (1.0f / 512.0f);
    const float inv = 1.0f / sqrtf(var + 1e-5f);
    Y[m * DDIM + tid]       = d0 * inv * g[tid]       + b[tid];
    Y[m * DDIM + 256 + tid] = d1 * inv * g[256 + tid] + b[256 + tid];
}

// host-side helper: split-K small-M GEMM + finalize
static void smallM(const float* A, long lda, const float* B, long ldb,
                   const float* bias, float* Y, int ldy, int K, int N,
                   int do_relu, int perow, float* P, hipStream_t stream)
{
    const int BK = (K == 1024 && N == 2048) ? 128 : 64;
    const int KC = K / BK;
    dim3 blk(256);
    if (BK == 128)
        gemm32<128><<<dim3(N / 64, KC), blk, 0, stream>>>(A, lda, B, ldb, P, N);
    else
        gemm32<64><<<dim3(N / 64, KC), blk, 0, stream>>>(A, lda, B, ldb, P, N);
    finalize<<<dim3(N / 256, 32), blk, 0, stream>>>(P, KC, N, bias, Y, ldy, do_relu, perow);
}

extern "C" void kernel_launch(void* const* d_in, const int* in_sizes, int n_in,
                              void* d_out, int out_size, void* d_ws, size_t ws_size,
                              hipStream_t stream)
{
    const float* features = (const float*)d_in[0];
    const float* enc_w1 = (const float*)d_in[1];
    const float* enc_b1 = (const float*)d_in[2];
    const float* enc_w2 = (const float*)d_in[3];
    const float* enc_b2 = (const float*)d_in[4];
    const float* qkv_w  = (const float*)d_in[5];
    const float* qkv_b  = (const float*)d_in[6];
    const float* lam    = (const float*)d_in[7];
    const float* out_w  = (const float*)d_in[8];
    const float* out_b  = (const float*)d_in[9];
    const float* ln1_g  = (const float*)d_in[10];
    const float* ln1_b  = (const float*)d_in[11];
    const float* ffn_w1 = (const float*)d_in[12];
    const float* ffn_b1 = (const float*)d_in[13];
    const float* ffn_w2 = (const float*)d_in[14];
    const float* ffn_b2 = (const float*)d_in[15];
    const float* ln2_g  = (const float*)d_in[16];
    const float* ln2_b  = (const float*)d_in[17];
    const float* act_w1 = (const float*)d_in[18];
    const float* act_b1 = (const float*)d_in[19];
    const float* act_w2 = (const float*)d_in[20];
    const float* act_b2 = (const float*)d_in[21];
    const float* act_w3 = (const float*)d_in[22];
    const float* act_b3 = (const float*)d_in[23];
    const float* cr_w1  = (const float*)d_in[24];
    const float* cr_b1  = (const float*)d_in[25];
    const float* cr_w2  = (const float*)d_in[26];
    const float* cr_b2  = (const float*)d_in[27];
    const float* cr_w3  = (const float*)d_in[28];
    const float* cr_b3  = (const float*)d_in[29];
    float* out = (float*)d_out;

    // workspace layout (floats), ~9.3 MB
    float* ws = (float*)d_ws;
    float* H1P    = ws;                       // 1024*512: enc hidden, then split-K partials
    float* Y31    = H1P + 1024 * 512;         // 1024*512
    float* KV     = Y31 + 1024 * 512;         // 1024*1024
    float* h32    = KV + 1024 * 1024;         // 32*512
    float* ylast  = h32 + 32 * 512;           // 32*512
    float* Q32    = ylast + 32 * 512;         // 32*512
    float* attn32 = Q32 + 32 * 512;           // 32*512
    float* attnp  = attn32 + 32 * 512;        // 32*512
    float* y1     = attnp + 32 * 512;         // 32*512
    float* y2     = y1 + 32 * 512;            // 32*512
    float* zbuf   = y2 + 32 * 512;            // 32*512
    float* hbuf   = zbuf + 32 * 512;          // 32*1024
    float* hbuf2  = hbuf + 32 * 1024;         // 32*2048

    dim3 blk(256);

    // encoder for batch 31 (full sequence)
    gemm_f32<<<dim3(DDIM / TN, TDIM / TM), blk, 0, stream>>>(
        features + (size_t)31 * TDIM * FDIM, FDIM, enc_w1, DDIM, enc_b1,
        H1P, DDIM, TDIM, DDIM, FDIM, 1, 0);
    gemm_f32<<<dim3(DDIM / TN, TDIM / TM), blk, 0, stream>>>(
        H1P, DDIM, enc_w2, DDIM, enc_b2,
        Y31, DDIM, TDIM, DDIM, DDIM, 1, 1);
    // K,V for batch 31 (qkv_w columns 512:1536)
    gemm_f32<<<dim3(1024 / TN, TDIM / TM), blk, 0, stream>>>(
        Y31, DDIM, qkv_w + 512, 1536, qkv_b + 512,
        KV, 1024, TDIM, 1024, DDIM, 0, 0);

    // last-timestep encoder rows for all 32 batches (H1P now free for partials)
    smallM(features + (size_t)(TDIM - 1) * FDIM, (long)TDIM * FDIM,
           enc_w1, DDIM, enc_b1, h32, DDIM, FDIM, DDIM, 1, -1, H1P, stream);
    smallM(h32, DDIM, enc_w2, DDIM, enc_b2, ylast, DDIM, DDIM, DDIM, 1, TDIM - 1, H1P, stream);
    // 32 Q rows of batch 31 (t = 32*i + 31 -> Y31 + 31*512, stride 32*512)
    smallM(Y31 + 31 * DDIM, 32 * DDIM, qkv_w, 1536, qkv_b, Q32, DDIM, DDIM, DDIM, 0, -1, H1P, stream);
    // attention
    attn_kernel<<<32, blk, 0, stream>>>(Q32, KV, lam, attn32);
    // out projection
    smallM(attn32, DDIM, out_w, DDIM, out_b, attnp, DDIM, DDIM, DDIM, 0, -1, H1P, stream);
    // LN1
    ln_kernel<<<32, blk, 0, stream>>>(ylast, attnp, ln1_g, ln1_b, y1);
    // FFN
    smallM(y1, DDIM, ffn_w1, FDIM, ffn_b1, hbuf, FDIM, DDIM, FDIM, 1, -1, H1P, stream);
    smallM(hbuf, FDIM, ffn_w2, DDIM, ffn_b2, zbuf, DDIM, FDIM, DDIM, 0, -1, H1P, stream);
    // LN2
    ln_kernel<<<32, blk, 0, stream>>>(y1, zbuf, ln2_g, ln2_b, y2);
    // actor head -> out[0:8192]
    smallM(y2, DDIM, act_w1, FDIM, act_b1, hbuf, FDIM, DDIM, FDIM, 1, -1, H1P, stream);
    smallM(hbuf, FDIM, act_w2, 2 * FDIM, act_b2, hbuf2, 2 * FDIM, FDIM, 2 * FDIM, 1, -1, H1P, stream);
    smallM(hbuf2, 2 * FDIM, act_w3, 256, act_b3, out, 256, 2 * FDIM, 256, 0, -1, H1P, stream);
    // critic head -> out[8192:16384]
    smallM(y2, DDIM, cr_w1, FDIM, cr_b1, hbuf, FDIM, DDIM, FDIM, 1, -1, H1P, stream);
    smallM(hbuf, FDIM, cr_w2, 2 * FDIM, cr_b2, hbuf2, 2 * FDIM, FDIM, 2 * FDIM, 1, -1, H1P, stream);
    smallM(hbuf2, 2 * FDIM, cr_w3, 256, cr_b3, out + 8192, 256, 2 * FDIM, 256, 0, -1, H1P, stream);
}

// Round 3
// 287.955 us; speedup vs baseline: 3.6207x; 1.3376x over previous
//
#include <hip/hip_runtime.h>
#include <math.h>

// Model dims
#define TDIM 1024   // context len
#define FDIM 1024
#define DDIM 512

__device__ __forceinline__ float posenc_val(int t, int c) {
    int j = c >> 1;
    float dv = expf(-9.210340371976184f * (float)(2 * j) * (1.0f / 512.0f));
    float arg = (float)t * dv;
    return (c & 1) ? cosf(arg) : sinf(arg);
}

// ---------------- Tiled fp32 GEMM: C = act(A @ B + bias) [+posenc] ----------------
#define TM 64
#define TN 64
#define TK 16

__global__ __launch_bounds__(256)
void gemm_f32(const float* __restrict__ A, int lda,
              const float* __restrict__ B, int ldb,
              const float* __restrict__ bias,
              float* __restrict__ C, int ldc,
              int M, int N, int K, int do_relu, int addpe)
{
    __shared__ float As[TK][TM + 4];
    __shared__ float Bs[TK][TN + 4];
    const int tid = threadIdx.x;
    const int bm = blockIdx.y * TM;
    const int bn = blockIdx.x * TN;
    const int tx = tid & 15, ty = tid >> 4;

    float acc[4][4] = {};

    for (int k0 = 0; k0 < K; k0 += TK) {
        #pragma unroll
        for (int p = 0; p < 4; ++p) {
            int r  = (tid >> 4) + p * 16;
            int kk = tid & 15;
            As[kk][r] = A[(size_t)(bm + r) * lda + k0 + kk];
        }
        #pragma unroll
        for (int p = 0; p < 4; ++p) {
            int kk = (tid >> 6) + p * 4;
            int c  = tid & 63;
            Bs[kk][c] = B[(size_t)(k0 + kk) * ldb + bn + c];
        }
        __syncthreads();
        #pragma unroll
        for (int kk = 0; kk < TK; ++kk) {
            float a[4], b[4];
            #pragma unroll
            for (int i = 0; i < 4; ++i) a[i] = As[kk][ty * 4 + i];
            #pragma unroll
            for (int j = 0; j < 4; ++j) b[j] = Bs[kk][tx * 4 + j];
            #pragma unroll
            for (int i = 0; i < 4; ++i)
                #pragma unroll
                for (int j = 0; j < 4; ++j)
                    acc[i][j] = fmaf(a[i], b[j], acc[i][j]);
        }
        __syncthreads();
    }

    #pragma unroll
    for (int i = 0; i < 4; ++i) {
        int m = bm + ty * 4 + i;
        #pragma unroll
        for (int j = 0; j < 4; ++j) {
            int n = bn + tx * 4 + j;
            float v = acc[i][j] + bias[n];
            if (do_relu) v = fmaxf(v, 0.f);
            if (addpe)   v += posenc_val(m, n);
            C[(size_t)m * ldc + n] = v;
        }
    }
}

// ---------------- split-K small-M GEMM: P[kc] = A(32xBK slice) @ B(BKx64 tile) ----------------
template<int BK>
__global__ __launch_bounds__(256)
void gemm32(const float* __restrict__ A, long lda,
            const float* __restrict__ B, long ldb,
            float* __restrict__ P, int N)
{
    __shared__ float Xs[32][BK + 4];
    __shared__ float Ws[BK][64];
    const int tid = threadIdx.x;
    const int n0 = blockIdx.x * 64;
    const int k0 = blockIdx.y * BK;

    {
        const int m  = tid >> 3;
        const int ks = (tid & 7) * (BK / 8);
        const float* src = A + (size_t)m * lda + k0 + ks;
        #pragma unroll
        for (int j = 0; j < BK / 32; ++j) {
            float4 v = *(const float4*)(src + j * 4);
            *(float4*)&Xs[m][ks + j * 4] = v;
        }
    }
    #pragma unroll
    for (int it = 0; it < BK / 16; ++it) {
        int e4  = it * 256 + tid;
        int row = e4 >> 4;
        int c4  = e4 & 15;
        float4 v = *(const float4*)(B + (size_t)(k0 + row) * ldb + n0 + c4 * 4);
        *(float4*)&Ws[row][c4 * 4] = v;
    }
    __syncthreads();

    const int tx = tid & 31;
    const int ty = tid >> 5;
    float acc[4][2] = {};
    #pragma unroll 8
    for (int k = 0; k < BK; k += 4) {
        float4 xv[4];
        #pragma unroll
        for (int i = 0; i < 4; ++i) xv[i] = *(const float4*)&Xs[ty * 4 + i][k];
        #pragma unroll
        for (int j = 0; j < 4; ++j) {
            float2 w = *(const float2*)&Ws[k + j][tx * 2];
            #pragma unroll
            for (int i = 0; i < 4; ++i) {
                float x = ((const float*)&xv[i])[j];
                acc[i][0] = fmaf(x, w.x, acc[i][0]);
                acc[i][1] = fmaf(x, w.y, acc[i][1]);
            }
        }
    }

    float* dst = P + (size_t)blockIdx.y * 32 * N;
    #pragma unroll
    for (int i = 0; i < 4; ++i) {
        float2 v = make_float2(acc[i][0], acc[i][1]);
        *(float2*)(dst + (size_t)(ty * 4 + i) * N + n0 + tx * 2) = v;
    }
}

// ---------------- finalize: Y = act(sum_kc P + bias) [+posenc(perow)] ----------------
__global__ __launch_bounds__(256)
void finalize(const float* __restrict__ P, int KC, int N,
              const float* __restrict__ bias, float* __restrict__ Y, int ldy,
              int do_relu, int perow)
{
    const int n = blockIdx.x * 256 + threadIdx.x;
    const int m = blockIdx.y;
    float s = bias ? bias[n] : 0.f;
    for (int kc = 0; kc < KC; ++kc) s += P[(size_t)(kc * 32 + m) * N + n];
    if (do_relu) s = fmaxf(s, 0.f);
    if (perow >= 0) s += posenc_val(perow, n);
    Y[(size_t)m * ldy + n] = s;
}

// ---------------- attention scores: partial S_T over a 128-dim chunk ----------------
// grid (16, 4): bx -> 64 keys, by -> 128-dim chunk. Psc[by][s][i], i = query 0..31
__global__ __launch_bounds__(256)
void scores_kernel(const float* __restrict__ KV, const float* __restrict__ Q32,
                   float* __restrict__ Psc)
{
    __shared__ float Kt[64][132];   // float4-aligned stride
    __shared__ float Qt[32][133];   // odd stride -> conflict-free scalar reads
    const int tid = threadIdx.x;
    const int s0 = blockIdx.x * 64;
    const int k0 = blockIdx.y * 128;

    // K tile: 64 rows x 128 (float4 loads+stores)
    #pragma unroll
    for (int it = 0; it < 8; ++it) {
        int e4 = it * 256 + tid;           // 64*32 float4
        int r  = e4 >> 5;
        int c4 = e4 & 31;
        float4 v = *(const float4*)(KV + (size_t)(s0 + r) * 1024 + k0 + c4 * 4);
        *(float4*)&Kt[r][c4 * 4] = v;
    }
    // Q tile: 32 rows x 128 (float4 global load, scalar LDS stores)
    #pragma unroll
    for (int it = 0; it < 4; ++it) {
        int e4 = it * 256 + tid;           // 32*32 float4
        int r  = e4 >> 5;
        int c4 = e4 & 31;
        float4 v = *(const float4*)(Q32 + (size_t)r * 512 + k0 + c4 * 4);
        Qt[r][c4 * 4 + 0] = v.x;
        Qt[r][c4 * 4 + 1] = v.y;
        Qt[r][c4 * 4 + 2] = v.z;
        Qt[r][c4 * 4 + 3] = v.w;
    }
    __syncthreads();

    const int i  = tid & 31;    // query
    const int sg = tid >> 5;    // key group (8 keys)
    float acc[8] = {};
    for (int k = 0; k < 128; ++k) {
        float q = Qt[i][k];
        #pragma unroll
        for (int j = 0; j < 8; ++j)
            acc[j] = fmaf(Kt[sg * 8 + j][k], q, acc[j]);
    }
    float* dst = Psc + (size_t)blockIdx.y * 1024 * 32;
    #pragma unroll
    for (int j = 0; j < 8; ++j)
        dst[(size_t)(s0 + sg * 8 + j) * 32 + i] = acc[j];
}

// ---------------- dual softmax + diff: D[i][s] = a1 - lam*a2 ----------------
__global__ __launch_bounds__(256)
void softmax_diff(const float* __restrict__ Psc, const float* __restrict__ lam_p,
                  float* __restrict__ D)
{
    __shared__ float sc1[TDIM];
    __shared__ float sc2[TDIM];
    __shared__ float red[256];
    const int i = blockIdx.x;
    const int tid = threadIdx.x;
    const float scale = 0.08838834764831845f; // 1/sqrt(128)
    for (int s = tid; s < TDIM; s += 256) {
        float a = Psc[(size_t)(0 * 1024 + s) * 32 + i] + Psc[(size_t)(1 * 1024 + s) * 32 + i];
        float b = Psc[(size_t)(2 * 1024 + s) * 32 + i] + Psc[(size_t)(3 * 1024 + s) * 32 + i];
        sc1[s] = a * scale;
        sc2[s] = b * scale;
    }
    __syncthreads();
    float m1 = -INFINITY, m2 = -INFINITY;
    for (int s = tid; s < TDIM; s += 256) { m1 = fmaxf(m1, sc1[s]); m2 = fmaxf(m2, sc2[s]); }
    red[tid] = m1; __syncthreads();
    for (int o = 128; o > 0; o >>= 1) { if (tid < o) red[tid] = fmaxf(red[tid], red[tid + o]); __syncthreads(); }
    m1 = red[0]; __syncthreads();
    red[tid] = m2; __syncthreads();
    for (int o = 128; o > 0; o >>= 1) { if (tid < o) red[tid] = fmaxf(red[tid], red[tid + o]); __syncthreads(); }
    m2 = red[0]; __syncthreads();
    float t1 = 0.f, t2 = 0.f;
    for (int s = tid; s < TDIM; s += 256) { t1 += expf(sc1[s] - m1); t2 += expf(sc2[s] - m2); }
    red[tid] = t1; __syncthreads();
    for (int o = 128; o > 0; o >>= 1) { if (tid < o) red[tid] += red[tid + o]; __syncthreads(); }
    t1 = red[0]; __syncthreads();
    red[tid] = t2; __syncthreads();
    for (int o = 128; o > 0; o >>= 1) { if (tid < o) red[tid] += red[tid + o]; __syncthreads(); }
    t2 = red[0]; __syncthreads();
    const float inv1 = 1.f / t1, inv2 = 1.f / t2;
    const float lam = *lam_p;
    for (int s = tid; s < TDIM; s += 256)
        D[(size_t)i * TDIM + s] = expf(sc1[s] - m1) * inv1 - lam * expf(sc2[s] - m2) * inv2;
}

// ---------------- LayerNorm over 512: Y = LN(X + R) * g + b ----------------
__global__ __launch_bounds__(256)
void ln_kernel(const float* __restrict__ X, const float* __restrict__ R,
               const float* __restrict__ g, const float* __restrict__ b,
               float* __restrict__ Y)
{
    __shared__ float red[256];
    const int m = blockIdx.x;
    const int tid = threadIdx.x;
    float v0 = X[m * DDIM + tid]       + R[m * DDIM + tid];
    float v1 = X[m * DDIM + 256 + tid] + R[m * DDIM + 256 + tid];
    red[tid] = v0 + v1; __syncthreads();
    for (int o = 128; o > 0; o >>= 1) { if (tid < o) red[tid] += red[tid + o]; __syncthreads(); }
    const float mu = red[0] * (1.0f / 512.0f);
    __syncthreads();
    float d0 = v0 - mu, d1 = v1 - mu;
    red[tid] = d0 * d0 + d1 * d1; __syncthreads();
    for (int o = 128; o > 0; o >>= 1) { if (tid < o) red[tid] += red[tid + o]; __syncthreads(); }
    const float var = red[0] * (1.0f / 512.0f);
    const float inv = 1.0f / sqrtf(var + 1e-5f);
    Y[m * DDIM + tid]       = d0 * inv * g[tid]       + b[tid];
    Y[m * DDIM + 256 + tid] = d1 * inv * g[256 + tid] + b[256 + tid];
}

// host-side helper: split-K small-M GEMM + finalize
static void smallM(const float* A, long lda, const float* B, long ldb,
                   const float* bias, float* Y, int ldy, int K, int N,
                   int do_relu, int perow, float* P, hipStream_t stream)
{
    const int BK = (K == 1024 && N == 2048) ? 128 : 64;
    const int KC = K / BK;
    dim3 blk(256);
    if (BK == 128)
        gemm32<128><<<dim3(N / 64, KC), blk, 0, stream>>>(A, lda, B, ldb, P, N);
    else
        gemm32<64><<<dim3(N / 64, KC), blk, 0, stream>>>(A, lda, B, ldb, P, N);
    finalize<<<dim3(N / 256, 32), blk, 0, stream>>>(P, KC, N, bias, Y, ldy, do_relu, perow);
}

extern "C" void kernel_launch(void* const* d_in, const int* in_sizes, int n_in,
                              void* d_out, int out_size, void* d_ws, size_t ws_size,
                              hipStream_t stream)
{
    const float* features = (const float*)d_in[0];
    const float* enc_w1 = (const float*)d_in[1];
    const float* enc_b1 = (const float*)d_in[2];
    const float* enc_w2 = (const float*)d_in[3];
    const float* enc_b2 = (const float*)d_in[4];
    const float* qkv_w  = (const float*)d_in[5];
    const float* qkv_b  = (const float*)d_in[6];
    const float* lam    = (const float*)d_in[7];
    const float* out_w  = (const float*)d_in[8];
    const float* out_b  = (const float*)d_in[9];
    const float* ln1_g  = (const float*)d_in[10];
    const float* ln1_b  = (const float*)d_in[11];
    const float* ffn_w1 = (const float*)d_in[12];
    const float* ffn_b1 = (const float*)d_in[13];
    const float* ffn_w2 = (const float*)d_in[14];
    const float* ffn_b2 = (const float*)d_in[15];
    const float* ln2_g  = (const float*)d_in[16];
    const float* ln2_b  = (const float*)d_in[17];
    const float* act_w1 = (const float*)d_in[18];
    const float* act_b1 = (const float*)d_in[19];
    const float* act_w2 = (const float*)d_in[20];
    const float* act_b2 = (const float*)d_in[21];
    const float* act_w3 = (const float*)d_in[22];
    const float* act_b3 = (const float*)d_in[23];
    const float* cr_w1  = (const float*)d_in[24];
    const float* cr_b1  = (const float*)d_in[25];
    const float* cr_w2  = (const float*)d_in[26];
    const float* cr_b2  = (const float*)d_in[27];
    const float* cr_w3  = (const float*)d_in[28];
    const float* cr_b3  = (const float*)d_in[29];
    float* out = (float*)d_out;

    // workspace layout (floats), ~10 MB
    float* ws = (float*)d_ws;
    float* H1P    = ws;                       // 1024*512: enc hidden, then partials
    float* Y31    = H1P + 1024 * 512;         // 1024*512
    float* KV     = Y31 + 1024 * 512;         // 1024*1024
    float* Psc    = KV + 1024 * 1024;         // 4*1024*32
    float* Dbuf   = Psc + 4 * 1024 * 32;      // 32*1024
    float* h32    = Dbuf + 32 * 1024;         // 32*512
    float* ylast  = h32 + 32 * 512;           // 32*512
    float* Q32    = ylast + 32 * 512;         // 32*512
    float* attn32 = Q32 + 32 * 512;           // 32*512
    float* attnp  = attn32 + 32 * 512;        // 32*512
    float* y1     = attnp + 32 * 512;         // 32*512
    float* y2     = y1 + 32 * 512;            // 32*512
    float* zbuf   = y2 + 32 * 512;            // 32*512
    float* hbuf   = zbuf + 32 * 512;          // 32*1024
    float* hbuf2  = hbuf + 32 * 1024;         // 32*2048

    dim3 blk(256);

    // encoder for batch 31 (full sequence)
    gemm_f32<<<dim3(DDIM / TN, TDIM / TM), blk, 0, stream>>>(
        features + (size_t)31 * TDIM * FDIM, FDIM, enc_w1, DDIM, enc_b1,
        H1P, DDIM, TDIM, DDIM, FDIM, 1, 0);
    gemm_f32<<<dim3(DDIM / TN, TDIM / TM), blk, 0, stream>>>(
        H1P, DDIM, enc_w2, DDIM, enc_b2,
        Y31, DDIM, TDIM, DDIM, DDIM, 1, 1);
    // K,V for batch 31 (qkv_w columns 512:1536)
    gemm_f32<<<dim3(1024 / TN, TDIM / TM), blk, 0, stream>>>(
        Y31, DDIM, qkv_w + 512, 1536, qkv_b + 512,
        KV, 1024, TDIM, 1024, DDIM, 0, 0);

    // last-timestep encoder rows for all 32 batches (H1P now free for partials)
    smallM(features + (size_t)(TDIM - 1) * FDIM, (long)TDIM * FDIM,
           enc_w1, DDIM, enc_b1, h32, DDIM, FDIM, DDIM, 1, -1, H1P, stream);
    smallM(h32, DDIM, enc_w2, DDIM, enc_b2, ylast, DDIM, DDIM, DDIM, 1, TDIM - 1, H1P, stream);
    // 32 Q rows of batch 31 (t = 32*i + 31)
    smallM(Y31 + 31 * DDIM, 32 * DDIM, qkv_w, 1536, qkv_b, Q32, DDIM, DDIM, DDIM, 0, -1, H1P, stream);

    // attention: scores -> softmax/diff -> PV
    scores_kernel<<<dim3(16, 4), blk, 0, stream>>>(KV, Q32, Psc);
    softmax_diff<<<32, blk, 0, stream>>>(Psc, lam, Dbuf);
    gemm32<64><<<dim3(512 / 64, 16), blk, 0, stream>>>(Dbuf, 1024, KV + 512, 1024, H1P, 512);
    finalize<<<dim3(512 / 256, 32), blk, 0, stream>>>(H1P, 16, 512, (const float*)nullptr, attn32, 512, 0, -1);

    // out projection
    smallM(attn32, DDIM, out_w, DDIM, out_b, attnp, DDIM, DDIM, DDIM, 0, -1, H1P, stream);
    // LN1
    ln_kernel<<<32, blk, 0, stream>>>(ylast, attnp, ln1_g, ln1_b, y1);
    // FFN
    smallM(y1, DDIM, ffn_w1, FDIM, ffn_b1, hbuf, FDIM, DDIM, FDIM, 1, -1, H1P, stream);
    smallM(hbuf, FDIM, ffn_w2, DDIM, ffn_b2, zbuf, DDIM, FDIM, DDIM, 0, -1, H1P, stream);
    // LN2
    ln_kernel<<<32, blk, 0, stream>>>(y1, zbuf, ln2_g, ln2_b, y2);
    // actor head -> out[0:8192]
    smallM(y2, DDIM, act_w1, FDIM, act_b1, hbuf, FDIM, DDIM, FDIM, 1, -1, H1P, stream);
    smallM(hbuf, FDIM, act_w2, 2 * FDIM, act_b2, hbuf2, 2 * FDIM, FDIM, 2 * FDIM, 1, -1, H1P, stream);
    smallM(hbuf2, 2 * FDIM, act_w3, 256, act_b3, out, 256, 2 * FDIM, 256, 0, -1, H1P, stream);
    // critic head -> out[8192:16384]
    smallM(y2, DDIM, cr_w1, FDIM, cr_b1, hbuf, FDIM, DDIM, FDIM, 1, -1, H1P, stream);
    smallM(hbuf, FDIM, cr_w2, 2 * FDIM, cr_b2, hbuf2, 2 * FDIM, FDIM, 2 * FDIM, 1, -1, H1P, stream);
    smallM(hbuf2, 2 * FDIM, cr_w3, 256, cr_b3, out + 8192, 256, 2 * FDIM, 256, 0, -1, H1P, stream);
}

// Round 4
// 175.591 us; speedup vs baseline: 5.9377x; 1.6399x over previous
//
#include <hip/hip_runtime.h>
#include <hip/hip_bf16.h>
#include <math.h>

// Model dims
#define TDIM 1024   // context len
#define FDIM 1024
#define DDIM 512

typedef __attribute__((ext_vector_type(8))) short bf16x8;
typedef __attribute__((ext_vector_type(4))) float f32x4;

__device__ __forceinline__ float posenc_val(int t, int c) {
    int j = c >> 1;
    float dv = expf(-9.210340371976184f * (float)(2 * j) * (1.0f / 512.0f));
    float arg = (float)t * dv;
    return (c & 1) ? cosf(arg) : sinf(arg);
}

__device__ __forceinline__ ushort f2bf(float f) {
    __hip_bfloat16 h = __float2bfloat16(f);
    return *reinterpret_cast<ushort*>(&h);
}

// ---------------- convert f32 -> bf16 (flat, vectorized) ----------------
__global__ __launch_bounds__(256)
void conv_bf16(const float* __restrict__ src, ushort* __restrict__ dst, int n4)
{
    int i = blockIdx.x * 256 + threadIdx.x;
    if (i < n4) {
        float4 v = ((const float4*)src)[i];
        ushort4 o;
        o.x = f2bf(v.x); o.y = f2bf(v.y); o.z = f2bf(v.z); o.w = f2bf(v.w);
        ((ushort4*)dst)[i] = o;
    }
}

// ---------------- convert+transpose: W[K][ldw] cols[col0:col0+N) -> Wt[N][K] bf16 ----------------
// grid (N/32, K/32), 256 threads
__global__ __launch_bounds__(256)
void convT_bf16(const float* __restrict__ W, int ldw, int col0,
                ushort* __restrict__ Wt, int K)
{
    __shared__ float t[32][33];
    const int k0 = blockIdx.y * 32, n0 = blockIdx.x * 32;
    const int x = threadIdx.x & 31, y = threadIdx.x >> 5;
    #pragma unroll
    for (int yy = y; yy < 32; yy += 8)
        t[yy][x] = W[(size_t)(k0 + yy) * ldw + col0 + n0 + x];
    __syncthreads();
    #pragma unroll
    for (int yy = y; yy < 32; yy += 8)
        Wt[(size_t)(n0 + yy) * K + k0 + x] = f2bf(t[x][yy]);
}

// ---------------- MFMA bf16 GEMM: C = act(A @ Bt^T + bias) [+posenc] ----------------
// A: M x K bf16 row-major; Bt: N x K bf16 row-major. 64x64 tile/block, 4 waves 2x2.
// Outputs: optional f32 C (ldc) and optional bf16 Cbf (ldcb).
__global__ __launch_bounds__(256)
void mfma_gemm(const ushort* __restrict__ A, const ushort* __restrict__ Bt,
               const float* __restrict__ bias,
               float* __restrict__ C, int ldc,
               ushort* __restrict__ Cbf, int ldcb,
               int K, int relu, int addpe)
{
    __shared__ __align__(16) ushort Al[64 * 64];
    __shared__ __align__(16) ushort Bl[64 * 64];
    const int tid = threadIdx.x;
    const int m0 = blockIdx.y * 64;
    const int n0 = blockIdx.x * 64;
    const int lane = tid & 63;
    const int wv = tid >> 6;
    const int wr = wv >> 1, wc = wv & 1;     // 2x2 waves of 32x32
    const int fr = lane & 15, g = lane >> 4; // fragment row/col & k-group

    f32x4 acc[2][2] = {};

    const int r0 = tid >> 3;   // staging row (0..31), +32 on second slot
    const int c0 = tid & 7;    // 16B slot within row

    for (int k0 = 0; k0 < K; k0 += 64) {
        #pragma unroll
        for (int it = 0; it < 2; ++it) {
            int r = r0 + it * 32;
            uint4 va = *(const uint4*)(A + (size_t)(m0 + r) * K + k0 + c0 * 8);
            *(uint4*)((char*)Al + r * 128 + ((c0 ^ (r & 7)) << 4)) = va;
            uint4 vb = *(const uint4*)(Bt + (size_t)(n0 + r) * K + k0 + c0 * 8);
            *(uint4*)((char*)Bl + r * 128 + ((c0 ^ (r & 7)) << 4)) = vb;
        }
        __syncthreads();
        #pragma unroll
        for (int h = 0; h < 2; ++h) {
            bf16x8 af[2], bff[2];
            #pragma unroll
            for (int i = 0; i < 2; ++i) {
                int row = wr * 32 + i * 16 + fr;
                af[i] = *(const bf16x8*)((const char*)Al + row * 128 + (((h * 4 + g) ^ (row & 7)) << 4));
                int col = wc * 32 + i * 16 + fr;
                bff[i] = *(const bf16x8*)((const char*)Bl + col * 128 + (((h * 4 + g) ^ (col & 7)) << 4));
            }
            #pragma unroll
            for (int i = 0; i < 2; ++i)
                #pragma unroll
                for (int j = 0; j < 2; ++j)
                    acc[i][j] = __builtin_amdgcn_mfma_f32_16x16x32_bf16(af[i], bff[j], acc[i][j], 0, 0, 0);
        }
        __syncthreads();
    }

    // epilogue: C/D layout col = lane&15, row = (lane>>4)*4 + reg
    #pragma unroll
    for (int j = 0; j < 2; ++j) {
        int n = n0 + wc * 32 + j * 16 + fr;
        float bv = bias ? bias[n] : 0.f;
        #pragma unroll
        for (int i = 0; i < 2; ++i) {
            #pragma unroll
            for (int q = 0; q < 4; ++q) {
                int m = m0 + wr * 32 + i * 16 + g * 4 + q;
                float v = acc[i][j][q] + bv;
                if (relu) v = fmaxf(v, 0.f);
                if (addpe) v += posenc_val(m, n);
                if (C)   C[(size_t)m * ldc + n] = v;
                if (Cbf) Cbf[(size_t)m * ldcb + n] = f2bf(v);
            }
        }
    }
}

// ---------------- split-K small-M GEMM (dual via blockIdx.z) ----------------
// grid (N/64, K/BK, nz). Partials P[(z*KC+kc)*32][N].
template<int BK>
__global__ __launch_bounds__(256)
void gemm32d(const float* __restrict__ X0, const float* __restrict__ X1, long lda,
             const float* __restrict__ W0, const float* __restrict__ W1, long ldb,
             float* __restrict__ P, int N)
{
    __shared__ float Xs[32][BK + 4];
    __shared__ float Ws[BK][64];
    const float* A = blockIdx.z ? X1 : X0;
    const float* B = blockIdx.z ? W1 : W0;
    const int tid = threadIdx.x;
    const int n0 = blockIdx.x * 64;
    const int k0 = blockIdx.y * BK;

    {
        const int m  = tid >> 3;
        const int ks = (tid & 7) * (BK / 8);
        const float* src = A + (size_t)m * lda + k0 + ks;
        #pragma unroll
        for (int j = 0; j < BK / 32; ++j) {
            float4 v = *(const float4*)(src + j * 4);
            *(float4*)&Xs[m][ks + j * 4] = v;
        }
    }
    #pragma unroll
    for (int it = 0; it < BK / 16; ++it) {
        int e4  = it * 256 + tid;
        int row = e4 >> 4;
        int c4  = e4 & 15;
        float4 v = *(const float4*)(B + (size_t)(k0 + row) * ldb + n0 + c4 * 4);
        *(float4*)&Ws[row][c4 * 4] = v;
    }
    __syncthreads();

    const int tx = tid & 31;
    const int ty = tid >> 5;
    float acc[4][2] = {};
    #pragma unroll 8
    for (int k = 0; k < BK; k += 4) {
        float4 xv[4];
        #pragma unroll
        for (int i = 0; i < 4; ++i) xv[i] = *(const float4*)&Xs[ty * 4 + i][k];
        #pragma unroll
        for (int j = 0; j < 4; ++j) {
            float2 w = *(const float2*)&Ws[k + j][tx * 2];
            #pragma unroll
            for (int i = 0; i < 4; ++i) {
                float x = ((const float*)&xv[i])[j];
                acc[i][0] = fmaf(x, w.x, acc[i][0]);
                acc[i][1] = fmaf(x, w.y, acc[i][1]);
            }
        }
    }

    float* dst = P + (size_t)(blockIdx.z * gridDim.y + blockIdx.y) * 32 * N;
    #pragma unroll
    for (int i = 0; i < 4; ++i) {
        float2 v = make_float2(acc[i][0], acc[i][1]);
        *(float2*)(dst + (size_t)(ty * 4 + i) * N + n0 + tx * 2) = v;
    }
}

// ---------------- finalize (dual): Y = act(sum_kc P + bias) [+posenc(perow)] ----------------
__global__ __launch_bounds__(256)
void finalized(const float* __restrict__ P, int KC, int N,
               const float* __restrict__ b0, const float* __restrict__ b1,
               float* __restrict__ Y0, float* __restrict__ Y1, int ldy,
               int do_relu, int perow)
{
    const int z = blockIdx.z;
    const float* bias = z ? b1 : b0;
    float* Y = z ? Y1 : Y0;
    const float* Pz = P + (size_t)z * KC * 32 * N;
    const int n = blockIdx.x * 256 + threadIdx.x;
    const int m = blockIdx.y;
    float s = bias ? bias[n] : 0.f;
    for (int kc = 0; kc < KC; ++kc) s += Pz[(size_t)(kc * 32 + m) * N + n];
    if (do_relu) s = fmaxf(s, 0.f);
    if (perow >= 0) s += posenc_val(perow, n);
    Y[(size_t)m * ldy + n] = s;
}

// ---------------- attention scores: partial S_T over a 128-dim chunk ----------------
__global__ __launch_bounds__(256)
void scores_kernel(const float* __restrict__ KV, const float* __restrict__ Q32,
                   float* __restrict__ Psc)
{
    __shared__ float Kt[64][132];
    __shared__ float Qt[32][133];
    const int tid = threadIdx.x;
    const int s0 = blockIdx.x * 64;
    const int k0 = blockIdx.y * 128;

    #pragma unroll
    for (int it = 0; it < 8; ++it) {
        int e4 = it * 256 + tid;
        int r  = e4 >> 5;
        int c4 = e4 & 31;
        float4 v = *(const float4*)(KV + (size_t)(s0 + r) * 1024 + k0 + c4 * 4);
        *(float4*)&Kt[r][c4 * 4] = v;
    }
    #pragma unroll
    for (int it = 0; it < 4; ++it) {
        int e4 = it * 256 + tid;
        int r  = e4 >> 5;
        int c4 = e4 & 31;
        float4 v = *(const float4*)(Q32 + (size_t)r * 512 + k0 + c4 * 4);
        Qt[r][c4 * 4 + 0] = v.x;
        Qt[r][c4 * 4 + 1] = v.y;
        Qt[r][c4 * 4 + 2] = v.z;
        Qt[r][c4 * 4 + 3] = v.w;
    }
    __syncthreads();

    const int i  = tid & 31;
    const int sg = tid >> 5;
    float acc[8] = {};
    for (int k = 0; k < 128; ++k) {
        float q = Qt[i][k];
        #pragma unroll
        for (int j = 0; j < 8; ++j)
            acc[j] = fmaf(Kt[sg * 8 + j][k], q, acc[j]);
    }
    float* dst = Psc + (size_t)blockIdx.y * 1024 * 32;
    #pragma unroll
    for (int j = 0; j < 8; ++j)
        dst[(size_t)(s0 + sg * 8 + j) * 32 + i] = acc[j];
}

// ---------------- dual softmax + diff: D[i][s] = a1 - lam*a2 ----------------
__global__ __launch_bounds__(256)
void softmax_diff(const float* __restrict__ Psc, const float* __restrict__ lam_p,
                  float* __restrict__ D)
{
    __shared__ float sc1[TDIM];
    __shared__ float sc2[TDIM];
    __shared__ float red[256];
    const int i = blockIdx.x;
    const int tid = threadIdx.x;
    const float scale = 0.08838834764831845f; // 1/sqrt(128)
    for (int s = tid; s < TDIM; s += 256) {
        float a = Psc[(size_t)(0 * 1024 + s) * 32 + i] + Psc[(size_t)(1 * 1024 + s) * 32 + i];
        float b = Psc[(size_t)(2 * 1024 + s) * 32 + i] + Psc[(size_t)(3 * 1024 + s) * 32 + i];
        sc1[s] = a * scale;
        sc2[s] = b * scale;
    }
    __syncthreads();
    float m1 = -INFINITY, m2 = -INFINITY;
    for (int s = tid; s < TDIM; s += 256) { m1 = fmaxf(m1, sc1[s]); m2 = fmaxf(m2, sc2[s]); }
    red[tid] = m1; __syncthreads();
    for (int o = 128; o > 0; o >>= 1) { if (tid < o) red[tid] = fmaxf(red[tid], red[tid + o]); __syncthreads(); }
    m1 = red[0]; __syncthreads();
    red[tid] = m2; __syncthreads();
    for (int o = 128; o > 0; o >>= 1) { if (tid < o) red[tid] = fmaxf(red[tid], red[tid + o]); __syncthreads(); }
    m2 = red[0]; __syncthreads();
    float t1 = 0.f, t2 = 0.f;
    for (int s = tid; s < TDIM; s += 256) { t1 += expf(sc1[s] - m1); t2 += expf(sc2[s] - m2); }
    red[tid] = t1; __syncthreads();
    for (int o = 128; o > 0; o >>= 1) { if (tid < o) red[tid] += red[tid + o]; __syncthreads(); }
    t1 = red[0]; __syncthreads();
    red[tid] = t2; __syncthreads();
    for (int o = 128; o > 0; o >>= 1) { if (tid < o) red[tid] += red[tid + o]; __syncthreads(); }
    t2 = red[0]; __syncthreads();
    const float inv1 = 1.f / t1, inv2 = 1.f / t2;
    const float lam = *lam_p;
    for (int s = tid; s < TDIM; s += 256)
        D[(size_t)i * TDIM + s] = expf(sc1[s] - m1) * inv1 - lam * expf(sc2[s] - m2) * inv2;
}

// ---------------- LayerNorm over 512: Y = LN(X + R) * g + b ----------------
__global__ __launch_bounds__(256)
void ln_kernel(const float* __restrict__ X, const float* __restrict__ R,
               const float* __restrict__ g, const float* __restrict__ b,
               float* __restrict__ Y)
{
    __shared__ float red[256];
    const int m = blockIdx.x;
    const int tid = threadIdx.x;
    float v0 = X[m * DDIM + tid]       + R[m * DDIM + tid];
    float v1 = X[m * DDIM + 256 + tid] + R[m * DDIM + 256 + tid];
    red[tid] = v0 + v1; __syncthreads();
    for (int o = 128; o > 0; o >>= 1) { if (tid < o) red[tid] += red[tid + o]; __syncthreads(); }
    const float mu = red[0] * (1.0f / 512.0f);
    __syncthreads();
    float d0 = v0 - mu, d1 = v1 - mu;
    red[tid] = d0 * d0 + d1 * d1; __syncthreads();
    for (int o = 128; o > 0; o >>= 1) { if (tid < o) red[tid] += red[tid + o]; __syncthreads(); }
    const float var = red[0] * (1.0f / 512.0f);
    const float inv = 1.0f / sqrtf(var + 1e-5f);
    Y[m * DDIM + tid]       = d0 * inv * g[tid]       + b[tid];
    Y[m * DDIM + 256 + tid] = d1 * inv * g[256 + tid] + b[256 + tid];
}

// host-side helper: split-K small-M GEMM + finalize (dual-capable)
static void smallM2(const float* A0, const float* A1, long lda,
                    const float* B0, const float* B1, long ldb,
                    const float* b0, const float* b1,
                    float* Y0, float* Y1, int ldy, int K, int N,
                    int relu, int perow, float* P, int nz, hipStream_t stream)
{
    const int BK = (K == 1024 && N == 2048) ? 128 : 64;
    const int KC = K / BK;
    dim3 blk(256);
    if (BK == 128)
        gemm32d<128><<<dim3(N / 64, KC, nz), blk, 0, stream>>>(A0, A1, lda, B0, B1, ldb, P, N);
    else
        gemm32d<64><<<dim3(N / 64, KC, nz), blk, 0, stream>>>(A0, A1, lda, B0, B1, ldb, P, N);
    finalized<<<dim3(N / 256, 32, nz), blk, 0, stream>>>(P, KC, N, b0, b1, Y0, Y1, ldy, relu, perow);
}

extern "C" void kernel_launch(void* const* d_in, const int* in_sizes, int n_in,
                              void* d_out, int out_size, void* d_ws, size_t ws_size,
                              hipStream_t stream)
{
    const float* features = (const float*)d_in[0];
    const float* enc_w1 = (const float*)d_in[1];
    const float* enc_b1 = (const float*)d_in[2];
    const float* enc_w2 = (const float*)d_in[3];
    const float* enc_b2 = (const float*)d_in[4];
    const float* qkv_w  = (const float*)d_in[5];
    const float* qkv_b  = (const float*)d_in[6];
    const float* lam    = (const float*)d_in[7];
    const float* out_w  = (const float*)d_in[8];
    const float* out_b  = (const float*)d_in[9];
    const float* ln1_g  = (const float*)d_in[10];
    const float* ln1_b  = (const float*)d_in[11];
    const float* ffn_w1 = (const float*)d_in[12];
    const float* ffn_b1 = (const float*)d_in[13];
    const float* ffn_w2 = (const float*)d_in[14];
    const float* ffn_b2 = (const float*)d_in[15];
    const float* ln2_g  = (const float*)d_in[16];
    const float* ln2_b  = (const float*)d_in[17];
    const float* act_w1 = (const float*)d_in[18];
    const float* act_b1 = (const float*)d_in[19];
    const float* act_w2 = (const float*)d_in[20];
    const float* act_b2 = (const float*)d_in[21];
    const float* act_w3 = (const float*)d_in[22];
    const float* act_b3 = (const float*)d_in[23];
    const float* cr_w1  = (const float*)d_in[24];
    const float* cr_b1  = (const float*)d_in[25];
    const float* cr_w2  = (const float*)d_in[26];
    const float* cr_b2  = (const float*)d_in[27];
    const float* cr_w3  = (const float*)d_in[28];
    const float* cr_b3  = (const float*)d_in[29];
    float* out = (float*)d_out;

    // ---------------- workspace layout (bytes) ----------------
    char* base = (char*)d_ws;
    // region0: bf16 staging for the encoder path; reused later as split-K partials
    ushort* feat_bf = (ushort*)(base + 0);               // 1024x1024  (2 MB)
    ushort* w1T     = (ushort*)(base + (2u << 20));      // 512x1024   (1 MB)
    ushort* w2T     = (ushort*)(base + (3u << 20));      // 512x512    (0.5 MB)
    ushort* kvwT    = (ushort*)(base + 3670016);         // 1024x512   (1 MB)  @3.5MB
    float*  Ppart   = (float*)(base + 0);                // partials (<=4 MB), after gemms done
    ushort* H1bf    = (ushort*)(base + 4718592);         // 1024x512   (1 MB)  @4.5MB
    float*  Y31     = (float*)(base + 5767168);          // 1024x512   (2 MB)  @5.5MB
    ushort* Y31bf   = (ushort*)(base + 7864320);         // 1024x512   (1 MB)  @7.5MB
    float*  KV      = (float*)(base + 8912896);          // 1024x1024  (4 MB)  @8.5MB
    float*  Psc     = (float*)(base + 13107200);         // 4x1024x32  (0.5MB) @12.5MB
    float*  Dbuf    = (float*)(base + 13631488);         // 32x1024    (128KB) @13MB
    float*  h32     = (float*)(base + 13762560);         // 32x512 each (64KB)
    float*  ylast   = h32    + 32 * 512;
    float*  Q32     = ylast  + 32 * 512;
    float*  attn32  = Q32    + 32 * 512;
    float*  attnp   = attn32 + 32 * 512;
    float*  y1      = attnp  + 32 * 512;
    float*  y2      = y1     + 32 * 512;
    float*  zbuf    = y2     + 32 * 512;
    float*  hbufA   = zbuf   + 32 * 512;    // 32x1024
    float*  hbufC   = hbufA  + 32 * 1024;   // 32x1024
    float*  hbuf2A  = hbufC  + 32 * 1024;   // 32x2048
    float*  hbuf2C  = hbuf2A + 32 * 2048;   // 32x2048

    dim3 blk(256);

    // ---- convert inputs to bf16 (features batch 31; weights transposed) ----
    conv_bf16<<<1024, blk, 0, stream>>>(features + (size_t)31 * TDIM * FDIM, feat_bf, 262144);
    convT_bf16<<<dim3(16, 32), blk, 0, stream>>>(enc_w1, DDIM, 0, w1T, FDIM);
    convT_bf16<<<dim3(16, 16), blk, 0, stream>>>(enc_w2, DDIM, 0, w2T, DDIM);
    convT_bf16<<<dim3(32, 16), blk, 0, stream>>>(qkv_w, 1536, 512, kvwT, DDIM);

    // ---- encoder for batch 31 + KV, via MFMA ----
    // H1bf = relu(feat @ enc_w1 + b1)          (bf16 out only)
    mfma_gemm<<<dim3(8, 16), blk, 0, stream>>>(feat_bf, w1T, enc_b1,
                                               (float*)nullptr, 0, H1bf, DDIM, FDIM, 1, 0);
    // Y31 = relu(H1 @ enc_w2 + b2) + posenc    (f32 + bf16 out)
    mfma_gemm<<<dim3(8, 16), blk, 0, stream>>>(H1bf, w2T, enc_b2,
                                               Y31, DDIM, Y31bf, DDIM, DDIM, 1, 1);
    // KV = Y31 @ qkv_w[:,512:1536] + b         (f32 out)
    mfma_gemm<<<dim3(16, 16), blk, 0, stream>>>(Y31bf, kvwT, qkv_b + 512,
                                                KV, 1024, (ushort*)nullptr, 0, DDIM, 0, 0);

    // ---- last-timestep encoder rows for all 32 batches (region0 now free) ----
    smallM2(features + (size_t)(TDIM - 1) * FDIM, nullptr, (long)TDIM * FDIM,
            enc_w1, nullptr, DDIM, enc_b1, nullptr, h32, nullptr, DDIM,
            FDIM, DDIM, 1, -1, Ppart, 1, stream);
    smallM2(h32, nullptr, DDIM, enc_w2, nullptr, DDIM, enc_b2, nullptr,
            ylast, nullptr, DDIM, DDIM, DDIM, 1, TDIM - 1, Ppart, 1, stream);
    // 32 Q rows of batch 31 (t = 32*i + 31)
    smallM2(Y31 + 31 * DDIM, nullptr, 32 * DDIM, qkv_w, nullptr, 1536, qkv_b, nullptr,
            Q32, nullptr, DDIM, DDIM, DDIM, 0, -1, Ppart, 1, stream);

    // ---- attention: scores -> softmax/diff -> PV ----
    scores_kernel<<<dim3(16, 4), blk, 0, stream>>>(KV, Q32, Psc);
    softmax_diff<<<32, blk, 0, stream>>>(Psc, lam, Dbuf);
    gemm32d<64><<<dim3(8, 16, 1), blk, 0, stream>>>(Dbuf, nullptr, 1024, KV + 512, nullptr, 1024, Ppart, 512);
    finalized<<<dim3(2, 32, 1), blk, 0, stream>>>(Ppart, 16, 512, nullptr, nullptr, attn32, nullptr, 512, 0, -1);

    // ---- out projection, LN1, FFN, LN2 ----
    smallM2(attn32, nullptr, DDIM, out_w, nullptr, DDIM, out_b, nullptr,
            attnp, nullptr, DDIM, DDIM, DDIM, 0, -1, Ppart, 1, stream);
    ln_kernel<<<32, blk, 0, stream>>>(ylast, attnp, ln1_g, ln1_b, y1);
    smallM2(y1, nullptr, DDIM, ffn_w1, nullptr, FDIM, ffn_b1, nullptr,
            hbufA, nullptr, FDIM, DDIM, FDIM, 1, -1, Ppart, 1, stream);
    smallM2(hbufA, nullptr, FDIM, ffn_w2, nullptr, DDIM, ffn_b2, nullptr,
            zbuf, nullptr, DDIM, FDIM, DDIM, 0, -1, Ppart, 1, stream);
    ln_kernel<<<32, blk, 0, stream>>>(y1, zbuf, ln2_g, ln2_b, y2);

    // ---- actor + critic heads (dual dispatches) ----
    smallM2(y2, y2, DDIM, act_w1, cr_w1, FDIM, act_b1, cr_b1,
            hbufA, hbufC, FDIM, DDIM, FDIM, 1, -1, Ppart, 2, stream);
    smallM2(hbufA, hbufC, FDIM, act_w2, cr_w2, 2 * FDIM, act_b2, cr_b2,
            hbuf2A, hbuf2C, 2 * FDIM, FDIM, 2 * FDIM, 1, -1, Ppart, 2, stream);
    smallM2(hbuf2A, hbuf2C, 2 * FDIM, act_w3, cr_w3, 256, act_b3, cr_b3,
            out, out + 8192, 256, 2 * FDIM, 256, 0, -1, Ppart, 2, stream);
}

// Round 5
// 141.607 us; speedup vs baseline: 7.3627x; 1.2400x over previous
//
#include <hip/hip_runtime.h>
#include <hip/hip_bf16.h>
#include <math.h>

#define TDIM 1024
#define FDIM 1024
#define DDIM 512

typedef __attribute__((ext_vector_type(8))) short bf16x8;
typedef __attribute__((ext_vector_type(8))) ushort u16x8;
typedef __attribute__((ext_vector_type(4))) float f32x4;

__device__ __forceinline__ float posenc_val(int t, int c) {
    int j = c >> 1;
    float dv = expf(-9.210340371976184f * (float)(2 * j) * (1.0f / 512.0f));
    float arg = (float)t * dv;
    return (c & 1) ? cosf(arg) : sinf(arg);
}

__device__ __forceinline__ ushort f2bf(float f) {
    __hip_bfloat16 h = __float2bfloat16(f);
    return *reinterpret_cast<ushort*>(&h);
}

// ================= small-M (32-row) split-K GEMM body =================
// Computes Pout[by] = X32tile @ W(BKx64). X either direct (lda) or a
// reduce-on-load of producer partials Pin (KCx chunks, +xbias, relu).
template<int BK>
__device__ __forceinline__ void g32_body(
    const float* X, long lda,
    const float* Pin, int KCx, const float* xbias, int xrelu,
    const float* W, long ldb,
    float* Pout, int N, int K,
    int bx, int by, float* lds)
{
    float (*Xs)[BK + 4] = (float (*)[BK + 4])lds;
    float (*Ws)[64]     = (float (*)[64])(lds + 32 * (BK + 4));
    const int tid = threadIdx.x;
    const int n0 = bx * 64, k0 = by * BK;

    {
        const int m  = tid >> 3;
        const int ks = (tid & 7) * (BK / 8);
        if (Pin) {
            #pragma unroll
            for (int j = 0; j < BK / 32; ++j) {
                float4 a = make_float4(0.f, 0.f, 0.f, 0.f);
                for (int c = 0; c < KCx; ++c) {
                    float4 v = *(const float4*)(Pin + (size_t)(c * 32 + m) * K + k0 + ks + j * 4);
                    a.x += v.x; a.y += v.y; a.z += v.z; a.w += v.w;
                }
                if (xbias) {
                    float4 bv = *(const float4*)(xbias + k0 + ks + j * 4);
                    a.x += bv.x; a.y += bv.y; a.z += bv.z; a.w += bv.w;
                }
                if (xrelu) {
                    a.x = fmaxf(a.x, 0.f); a.y = fmaxf(a.y, 0.f);
                    a.z = fmaxf(a.z, 0.f); a.w = fmaxf(a.w, 0.f);
                }
                *(float4*)&Xs[m][ks + j * 4] = a;
            }
        } else {
            const float* src = X + (size_t)m * lda + k0 + ks;
            #pragma unroll
            for (int j = 0; j < BK / 32; ++j)
                *(float4*)&Xs[m][ks + j * 4] = *(const float4*)(src + j * 4);
        }
    }
    #pragma unroll
    for (int it = 0; it < BK / 16; ++it) {
        int e4  = it * 256 + tid;
        int row = e4 >> 4;
        int c4  = e4 & 15;
        *(float4*)&Ws[row][c4 * 4] = *(const float4*)(W + (size_t)(k0 + row) * ldb + n0 + c4 * 4);
    }
    __syncthreads();

    const int tx = tid & 31;
    const int ty = tid >> 5;
    float acc[4][2] = {};
    #pragma unroll 8
    for (int k = 0; k < BK; k += 4) {
        float4 xv[4];
        #pragma unroll
        for (int i = 0; i < 4; ++i) xv[i] = *(const float4*)&Xs[ty * 4 + i][k];
        #pragma unroll
        for (int j = 0; j < 4; ++j) {
            float2 w = *(const float2*)&Ws[k + j][tx * 2];
            #pragma unroll
            for (int i = 0; i < 4; ++i) {
                float x = ((const float*)&xv[i])[j];
                acc[i][0] = fmaf(x, w.x, acc[i][0]);
                acc[i][1] = fmaf(x, w.y, acc[i][1]);
            }
        }
    }
    float* dst = Pout + (size_t)by * 32 * N;
    #pragma unroll
    for (int i = 0; i < 4; ++i)
        *(float2*)(dst + (size_t)(ty * 4 + i) * N + n0 + tx * 2) = make_float2(acc[i][0], acc[i][1]);
}

// generic 3D-grid wrapper (z = dual set)
template<int BK>
__global__ __launch_bounds__(256) void g32k(
    const float* X0, const float* X1, long lda,
    const float* Pin0, const float* Pin1, int KCx,
    const float* xb0, const float* xb1, int xrelu,
    const float* W0, const float* W1, long ldb,
    float* Pout, int N, int K)
{
    __shared__ __align__(16) float lds[32 * (BK + 4) + BK * 64];
    const int z = blockIdx.z;
    g32_body<BK>(z ? X1 : X0, lda, z ? Pin1 : Pin0, KCx, z ? xb1 : xb0, xrelu,
                 z ? W1 : W0, ldb,
                 Pout + (size_t)z * gridDim.y * 32 * N,
                 N, K, blockIdx.x, blockIdx.y, lds);
}

// ================= convert+transpose body: W[K][ldw] -> Wt[N][K] bf16 =================
__device__ __forceinline__ void convT_body(const float* W, int ldw, int col0,
                                           ushort* Wt, int K, int bx, int by, float* lds)
{
    float (*t)[33] = (float (*)[33])lds;
    const int k0 = by * 32, n0 = bx * 32;
    const int x = threadIdx.x & 31, y = threadIdx.x >> 5;
    #pragma unroll
    for (int yy = y; yy < 32; yy += 8)
        t[yy][x] = W[(size_t)(k0 + yy) * ldw + col0 + n0 + x];
    __syncthreads();
    #pragma unroll
    for (int yy = y; yy < 32; yy += 8)
        Wt[(size_t)(n0 + yy) * K + k0 + x] = f2bf(t[x][yy]);
}

// ================= MFMA bf16 GEMM body (64x64 tile, 4 waves 2x2) =================
__device__ __forceinline__ void mfma_body(
    const void* Aptr, int af32, long lda,
    const ushort* Bt, const float* bias,
    float* C, int ldc, ushort* Cbf, int ldcb,
    int K, int relu, int addpe,
    int bx, int by, char* smem)
{
    ushort* Al = (ushort*)smem;
    ushort* Bl = Al + 64 * 64;
    const int tid = threadIdx.x;
    const int m0 = by * 64;
    const int n0 = bx * 64;
    const int lane = tid & 63;
    const int wv = tid >> 6;
    const int wr = wv >> 1, wc = wv & 1;
    const int fr = lane & 15, g = lane >> 4;

    f32x4 acc[2][2] = {};

    const int r0 = tid >> 3;
    const int c0 = tid & 7;

    for (int k0 = 0; k0 < K; k0 += 64) {
        #pragma unroll
        for (int it = 0; it < 2; ++it) {
            int r = r0 + it * 32;
            if (af32) {
                const float* Af = (const float*)Aptr;
                const float* s = Af + (size_t)(m0 + r) * lda + k0 + c0 * 8;
                float4 u = *(const float4*)s;
                float4 v = *(const float4*)(s + 4);
                u16x8 pv;
                pv[0] = f2bf(u.x); pv[1] = f2bf(u.y); pv[2] = f2bf(u.z); pv[3] = f2bf(u.w);
                pv[4] = f2bf(v.x); pv[5] = f2bf(v.y); pv[6] = f2bf(v.z); pv[7] = f2bf(v.w);
                *(u16x8*)((char*)Al + r * 128 + ((c0 ^ (r & 7)) << 4)) = pv;
            } else {
                const ushort* Au = (const ushort*)Aptr;
                uint4 va = *(const uint4*)(Au + (size_t)(m0 + r) * lda + k0 + c0 * 8);
                *(uint4*)((char*)Al + r * 128 + ((c0 ^ (r & 7)) << 4)) = va;
            }
            uint4 vb = *(const uint4*)(Bt + (size_t)(n0 + r) * K + k0 + c0 * 8);
            *(uint4*)((char*)Bl + r * 128 + ((c0 ^ (r & 7)) << 4)) = vb;
        }
        __syncthreads();
        #pragma unroll
        for (int h = 0; h < 2; ++h) {
            bf16x8 af[2], bff[2];
            #pragma unroll
            for (int i = 0; i < 2; ++i) {
                int row = wr * 32 + i * 16 + fr;
                af[i] = *(const bf16x8*)((const char*)Al + row * 128 + (((h * 4 + g) ^ (row & 7)) << 4));
                int col = wc * 32 + i * 16 + fr;
                bff[i] = *(const bf16x8*)((const char*)Bl + col * 128 + (((h * 4 + g) ^ (col & 7)) << 4));
            }
            #pragma unroll
            for (int i = 0; i < 2; ++i)
                #pragma unroll
                for (int j = 0; j < 2; ++j)
                    acc[i][j] = __builtin_amdgcn_mfma_f32_16x16x32_bf16(af[i], bff[j], acc[i][j], 0, 0, 0);
        }
        __syncthreads();
    }

    #pragma unroll
    for (int j = 0; j < 2; ++j) {
        int n = n0 + wc * 32 + j * 16 + fr;
        float bv = bias ? bias[n] : 0.f;
        #pragma unroll
        for (int i = 0; i < 2; ++i) {
            #pragma unroll
            for (int q = 0; q < 4; ++q) {
                int m = m0 + wr * 32 + i * 16 + g * 4 + q;
                float v = acc[i][j][q] + bv;
                if (relu) v = fmaxf(v, 0.f);
                if (addpe) v += posenc_val(m, n);
                if (C)   C[(size_t)m * ldc + n] = v;
                if (Cbf) Cbf[(size_t)m * ldcb + n] = f2bf(v);
            }
        }
    }
}

__global__ __launch_bounds__(256) void mfma_k(
    const void* A, int af32, long lda, const ushort* Bt, const float* bias,
    float* C, int ldc, ushort* Cbf, int ldcb, int K, int relu, int pe)
{
    __shared__ __align__(16) char smem[16384];
    mfma_body(A, af32, lda, Bt, bias, C, ldc, Cbf, ldcb, K, relu, pe,
              blockIdx.x, blockIdx.y, smem);
}

// ================= fused D1: weight transposes + enc-last stage1 partials =================
__global__ __launch_bounds__(256) void prep_k(
    const float* features, const float* enc_w1, const float* qkv_w, const float* enc_w2,
    ushort* w1T, ushort* w2T, ushort* qkvT, float* P_enc1)
{
    __shared__ __align__(16) float lds[6272];
    int t = blockIdx.x;
    if (t < 128) {
        g32_body<64>(features + (size_t)1023 * FDIM, (long)TDIM * FDIM,
                     nullptr, 0, nullptr, 0,
                     enc_w1, DDIM, P_enc1, 512, 1024, t & 7, t >> 3, lds);
    } else if (t < 640) {
        int u = t - 128;   // enc_w1: N=512(16 x-tiles) K=1024(32 y-tiles)
        convT_body(enc_w1, 512, 0, w1T, 1024, u & 15, u >> 4, lds);
    } else if (t < 896) {
        int u = t - 640;   // enc_w2: 16 x 16
        convT_body(enc_w2, 512, 0, w2T, 512, u & 15, u >> 4, lds);
    } else {
        int u = t - 896;   // qkv_w: N=1536(48) K=512(16)
        convT_body(qkv_w, 1536, 0, qkvT, 512, u % 48, u / 48, lds);
    }
}

// ================= fused D2: MFMA H1 + enc-last stage2 partials =================
__global__ __launch_bounds__(256) void stage2_k(
    const float* features31, const ushort* w1T, const float* enc_b1, ushort* H1bf,
    const float* P_enc1, const float* enc_w2, float* P_enc2)
{
    __shared__ __align__(16) char smem[25600];
    int t = blockIdx.x;
    if (t < 128) {
        mfma_body(features31, 1, 1024, w1T, enc_b1, nullptr, 0, H1bf, 512,
                  1024, 1, 0, t & 7, t >> 3, smem);
    } else {
        int u = t - 128;   // enc2: N=512(8) KC=8
        g32_body<64>(nullptr, 0, P_enc1, 16, enc_b1, 1,
                     enc_w2, 512, P_enc2, 512, 512, u & 7, u >> 3, (float*)smem);
    }
}

// ================= scores body + ylast finalize (fused D5) =================
__device__ void scores_body(const float* QKV, float* Psc, int bxs, int byc, char* smem)
{
    float (*Kt)[132] = (float (*)[132])smem;
    float (*Qt)[133] = (float (*)[133])(smem + 64 * 132 * 4);
    const int tid = threadIdx.x;
    const int s0 = bxs * 64;
    const int k0 = byc * 128;

    #pragma unroll
    for (int it = 0; it < 8; ++it) {
        int e4 = it * 256 + tid;
        int r  = e4 >> 5;
        int c4 = e4 & 31;
        float4 v = *(const float4*)(QKV + (size_t)(s0 + r) * 1536 + 512 + k0 + c4 * 4);
        *(float4*)&Kt[r][c4 * 4] = v;
    }
    #pragma unroll
    for (int it = 0; it < 4; ++it) {
        int e4 = it * 256 + tid;
        int r  = e4 >> 5;
        int c4 = e4 & 31;
        float4 v = *(const float4*)(QKV + (size_t)(32 * r + 31) * 1536 + k0 + c4 * 4);
        Qt[r][c4 * 4 + 0] = v.x;
        Qt[r][c4 * 4 + 1] = v.y;
        Qt[r][c4 * 4 + 2] = v.z;
        Qt[r][c4 * 4 + 3] = v.w;
    }
    __syncthreads();

    const int i  = tid & 31;
    const int sg = tid >> 5;
    float acc[8] = {};
    for (int k = 0; k < 128; ++k) {
        float q = Qt[i][k];
        #pragma unroll
        for (int j = 0; j < 8; ++j)
            acc[j] = fmaf(Kt[sg * 8 + j][k], q, acc[j]);
    }
    float* dst = Psc + (size_t)byc * 1024 * 32;
    #pragma unroll
    for (int j = 0; j < 8; ++j)
        dst[(size_t)(s0 + sg * 8 + j) * 32 + i] = acc[j];
}

__global__ __launch_bounds__(256) void stage5_k(
    const float* QKV, float* Psc,
    const float* P_enc2, const float* enc_b2, float* ylast)
{
    __shared__ __align__(16) char smem[50816];
    int t = blockIdx.x;
    if (t < 64) {
        scores_body(QKV, Psc, t & 15, t >> 4, smem);
    } else {
        int blk = t - 64;  // 8 blocks x 4 rows
        for (int idx = threadIdx.x; idx < 4 * 512; idx += 256) {
            int r = idx >> 9, c = idx & 511;
            int m = blk * 4 + r;
            float s = enc_b2[c];
            for (int cc = 0; cc < 8; ++cc) s += P_enc2[(size_t)(cc * 32 + m) * 512 + c];
            s = fmaxf(s, 0.f) + posenc_val(1023, c);
            ylast[m * 512 + c] = s;
        }
    }
}

// ================= dual softmax + diff =================
__global__ __launch_bounds__(256) void softmax_diff(
    const float* __restrict__ Psc, const float* __restrict__ lam_p, float* __restrict__ D)
{
    __shared__ float sc1[TDIM];
    __shared__ float sc2[TDIM];
    __shared__ float red[256];
    const int i = blockIdx.x;
    const int tid = threadIdx.x;
    const float scale = 0.08838834764831845f; // 1/sqrt(128)
    for (int s = tid; s < TDIM; s += 256) {
        float a = Psc[(size_t)(0 * 1024 + s) * 32 + i] + Psc[(size_t)(1 * 1024 + s) * 32 + i];
        float b = Psc[(size_t)(2 * 1024 + s) * 32 + i] + Psc[(size_t)(3 * 1024 + s) * 32 + i];
        sc1[s] = a * scale;
        sc2[s] = b * scale;
    }
    __syncthreads();
    float m1 = -INFINITY, m2 = -INFINITY;
    for (int s = tid; s < TDIM; s += 256) { m1 = fmaxf(m1, sc1[s]); m2 = fmaxf(m2, sc2[s]); }
    red[tid] = m1; __syncthreads();
    for (int o = 128; o > 0; o >>= 1) { if (tid < o) red[tid] = fmaxf(red[tid], red[tid + o]); __syncthreads(); }
    m1 = red[0]; __syncthreads();
    red[tid] = m2; __syncthreads();
    for (int o = 128; o > 0; o >>= 1) { if (tid < o) red[tid] = fmaxf(red[tid], red[tid + o]); __syncthreads(); }
    m2 = red[0]; __syncthreads();
    float t1 = 0.f, t2 = 0.f;
    for (int s = tid; s < TDIM; s += 256) { t1 += expf(sc1[s] - m1); t2 += expf(sc2[s] - m2); }
    red[tid] = t1; __syncthreads();
    for (int o = 128; o > 0; o >>= 1) { if (tid < o) red[tid] += red[tid + o]; __syncthreads(); }
    t1 = red[0]; __syncthreads();
    red[tid] = t2; __syncthreads();
    for (int o = 128; o > 0; o >>= 1) { if (tid < o) red[tid] += red[tid + o]; __syncthreads(); }
    t2 = red[0]; __syncthreads();
    const float inv1 = 1.f / t1, inv2 = 1.f / t2;
    const float lam = *lam_p;
    for (int s = tid; s < TDIM; s += 256)
        D[(size_t)i * TDIM + s] = expf(sc1[s] - m1) * inv1 - lam * expf(sc2[s] - m2) * inv2;
}

// ================= LN with reduce-on-load: Y = LN(R + sum(P)+bias)*g + b =================
__global__ __launch_bounds__(256) void ln_red(
    const float* __restrict__ Pin, int KC, const float* __restrict__ bias,
    const float* __restrict__ R, const float* __restrict__ g, const float* __restrict__ b,
    float* __restrict__ Y)
{
    __shared__ float red[256];
    const int m = blockIdx.x;
    const int tid = threadIdx.x;
    float v0 = bias ? bias[tid] : 0.f;
    float v1 = bias ? bias[tid + 256] : 0.f;
    for (int c = 0; c < KC; ++c) {
        v0 += Pin[(size_t)(c * 32 + m) * 512 + tid];
        v1 += Pin[(size_t)(c * 32 + m) * 512 + tid + 256];
    }
    v0 += R[m * 512 + tid];
    v1 += R[m * 512 + tid + 256];
    red[tid] = v0 + v1; __syncthreads();
    for (int o = 128; o > 0; o >>= 1) { if (tid < o) red[tid] += red[tid + o]; __syncthreads(); }
    const float mu = red[0] * (1.0f / 512.0f);
    __syncthreads();
    float d0 = v0 - mu, d1 = v1 - mu;
    red[tid] = d0 * d0 + d1 * d1; __syncthreads();
    for (int o = 128; o > 0; o >>= 1) { if (tid < o) red[tid] += red[tid + o]; __syncthreads(); }
    const float var = red[0] * (1.0f / 512.0f);
    const float inv = 1.0f / sqrtf(var + 1e-5f);
    Y[m * 512 + tid]       = d0 * inv * g[tid]       + b[tid];
    Y[m * 512 + 256 + tid] = d1 * inv * g[256 + tid] + b[256 + tid];
}

// ================= final head reduce -> out =================
__global__ __launch_bounds__(256) void fin_out(
    const float* __restrict__ P, const float* __restrict__ b0, const float* __restrict__ b1,
    float* __restrict__ out)
{
    const int m = blockIdx.x;
    const int z = blockIdx.y;
    const int n = threadIdx.x;
    const float* bias = z ? b1 : b0;
    const float* Pz = P + (size_t)z * 16 * 32 * 256;
    float s = bias[n];
    for (int c = 0; c < 16; ++c) s += Pz[(size_t)(c * 32 + m) * 256 + n];
    out[z * 8192 + m * 256 + n] = s;
}

extern "C" void kernel_launch(void* const* d_in, const int* in_sizes, int n_in,
                              void* d_out, int out_size, void* d_ws, size_t ws_size,
                              hipStream_t stream)
{
    const float* features = (const float*)d_in[0];
    const float* enc_w1 = (const float*)d_in[1];
    const float* enc_b1 = (const float*)d_in[2];
    const float* enc_w2 = (const float*)d_in[3];
    const float* enc_b2 = (const float*)d_in[4];
    const float* qkv_w  = (const float*)d_in[5];
    const float* qkv_b  = (const float*)d_in[6];
    const float* lam    = (const float*)d_in[7];
    const float* out_w  = (const float*)d_in[8];
    const float* out_b  = (const float*)d_in[9];
    const float* ln1_g  = (const float*)d_in[10];
    const float* ln1_b  = (const float*)d_in[11];
    const float* ffn_w1 = (const float*)d_in[12];
    const float* ffn_b1 = (const float*)d_in[13];
    const float* ffn_w2 = (const float*)d_in[14];
    const float* ffn_b2 = (const float*)d_in[15];
    const float* ln2_g  = (const float*)d_in[16];
    const float* ln2_b  = (const float*)d_in[17];
    const float* act_w1 = (const float*)d_in[18];
    const float* act_b1 = (const float*)d_in[19];
    const float* act_w2 = (const float*)d_in[20];
    const float* act_b2 = (const float*)d_in[21];
    const float* act_w3 = (const float*)d_in[22];
    const float* act_b3 = (const float*)d_in[23];
    const float* cr_w1  = (const float*)d_in[24];
    const float* cr_b1  = (const float*)d_in[25];
    const float* cr_w2  = (const float*)d_in[26];
    const float* cr_b2  = (const float*)d_in[27];
    const float* cr_w3  = (const float*)d_in[28];
    const float* cr_b3  = (const float*)d_in[29];
    float* out = (float*)d_out;

    // ---------------- workspace (byte offsets) ----------------
    char* base = (char*)d_ws;
    ushort* w1T    = (ushort*)(base + 0x000000);   // 512x1024  (1 MiB)
    ushort* w2T    = (ushort*)(base + 0x100000);   // 512x512   (0.5 MiB)
    ushort* qkvT   = (ushort*)(base + 0x180000);   // 1536x512  (1.5 MiB)
    ushort* H1bf   = (ushort*)(base + 0x300000);   // 1024x512  (1 MiB)
    ushort* Y31bf  = (ushort*)(base + 0x400000);   // 1024x512  (1 MiB)
    float*  QKV    = (float*)(base + 0x500000);    // 1024x1536 (6 MiB)
    float*  Psc    = (float*)(base + 0xB00000);    // 4x1024x32
    float*  Dbuf   = (float*)(base + 0xB80000);    // 32x1024
    float*  ylast  = (float*)(base + 0xBA0000);    // 32x512
    float*  y1     = (float*)(base + 0xBB0000);    // 32x512
    float*  y2     = (float*)(base + 0xBC0000);    // 32x512
    float*  P_enc1 = (float*)(base + 0xC00000);    // 16x32x512
    float*  P_enc2 = (float*)(base + 0xD00000);    // 8x32x512
    float*  P_attn = (float*)(base + 0xD80000);    // 16x32x512
    float*  P_atp  = (float*)(base + 0xE80000);    // 8x32x512
    float*  P_h    = (float*)(base + 0xF00000);    // 8x32x1024
    float*  P_z    = (float*)(base + 0x1000000);   // 16x32x512
    float*  P_a1   = (float*)(base + 0x1100000);   // 2x8x32x1024
    float*  P_a2   = (float*)(base + 0x1300000);   // 2x8x32x2048
    float*  P_a3   = (float*)(base + 0x1700000);   // 2x16x32x256

    const float* features31 = features + (size_t)31 * TDIM * FDIM;
    dim3 blk(256);
    const float* NPF = nullptr;

    // D1: weight transposes + enc-last stage1 partials
    prep_k<<<1664, blk, 0, stream>>>(features, enc_w1, qkv_w, enc_w2, w1T, w2T, qkvT, P_enc1);
    // D2: MFMA H1 (f32 A on-the-fly) + enc-last stage2 partials
    stage2_k<<<192, blk, 0, stream>>>(features31, w1T, enc_b1, H1bf, P_enc1, enc_w2, P_enc2);
    // D3: MFMA Y31bf = relu(H1 @ enc_w2 + b2) + posenc
    mfma_k<<<dim3(8, 16), blk, 0, stream>>>(H1bf, 0, 512, w2T, enc_b2,
                                            nullptr, 0, Y31bf, 512, 512, 1, 1);
    // D4: MFMA QKV = Y31 @ qkv_w + qkv_b  (f32, ld 1536)
    mfma_k<<<dim3(24, 16), blk, 0, stream>>>(Y31bf, 0, 512, qkvT, qkv_b,
                                             QKV, 1536, nullptr, 0, 512, 0, 0);
    // D5: scores partials + ylast finalize
    stage5_k<<<72, blk, 0, stream>>>(QKV, Psc, P_enc2, enc_b2, ylast);
    // D6: dual softmax + diff
    softmax_diff<<<32, blk, 0, stream>>>(Psc, lam, Dbuf);
    // D7: PV partials (Dbuf @ V)
    g32k<64><<<dim3(8, 16, 1), blk, 0, stream>>>(Dbuf, NPF, 1024, NPF, NPF, 0, NPF, NPF, 0,
                                                 QKV + 1024, NPF, 1536, P_attn, 512, 1024);
    // D8: out-projection partials (reduce P_attn on load)
    g32k<64><<<dim3(8, 8, 1), blk, 0, stream>>>(NPF, NPF, 0, P_attn, NPF, 16, NPF, NPF, 0,
                                                out_w, NPF, 512, P_atp, 512, 512);
    // D9: LN1
    ln_red<<<32, blk, 0, stream>>>(P_atp, 8, out_b, ylast, ln1_g, ln1_b, y1);
    // D10: FFN1 partials
    g32k<64><<<dim3(16, 8, 1), blk, 0, stream>>>(y1, NPF, 512, NPF, NPF, 0, NPF, NPF, 0,
                                                 ffn_w1, NPF, 1024, P_h, 1024, 512);
    // D11: FFN2 partials (reduce+relu P_h)
    g32k<64><<<dim3(8, 16, 1), blk, 0, stream>>>(NPF, NPF, 0, P_h, NPF, 8, ffn_b1, NPF, 1,
                                                 ffn_w2, NPF, 512, P_z, 512, 1024);
    // D12: LN2
    ln_red<<<32, blk, 0, stream>>>(P_z, 16, ffn_b2, y1, ln2_g, ln2_b, y2);
    // D13: heads layer1 (dual)
    g32k<64><<<dim3(16, 8, 2), blk, 0, stream>>>(y2, y2, 512, NPF, NPF, 0, NPF, NPF, 0,
                                                 act_w1, cr_w1, 1024, P_a1, 1024, 512);
    // D14: heads layer2 (dual, reduce+relu P_a1)
    g32k<128><<<dim3(32, 8, 2), blk, 0, stream>>>(NPF, NPF, 0, P_a1, P_a1 + 8 * 32 * 1024, 8,
                                                  act_b1, cr_b1, 1,
                                                  act_w2, cr_w2, 2048, P_a2, 2048, 1024);
    // D15: heads layer3 (dual, reduce+relu P_a2)
    g32k<128><<<dim3(4, 16, 2), blk, 0, stream>>>(NPF, NPF, 0, P_a2, P_a2 + 8 * 32 * 2048, 8,
                                                  act_b2, cr_b2, 1,
                                                  act_w3, cr_w3, 256, P_a3, 256, 2048);
    // D16: final reduce -> out
    fin_out<<<dim3(32, 2), blk, 0, stream>>>(P_a3, act_b3, cr_b3, out);
}